// Round 9
// baseline (691.951 us; speedup 1.0000x reference)
//
#include <hip/hip_runtime.h>
#include <hip/hip_bf16.h>

// MyTransformerEncoderBlock: B=4, S=2048, D=1024, H=16, dk=64, D_FF=4096
// Round 15:
//  - attn: kv-split x2. Each (head, 256-q-tile) handled by TWO blocks, one per
//    kv half (16 tiles each). Grid (64,16) = 1024 blocks = 4/CU = 16 waves/CU
//    WITH 64 q-rows/wave (halved LDS/FLOP) -- first config with both.
//    bx=bh -> head's K/V pinned to one XCD (r7's FETCH win, 139->27MB).
//    Partials: O halves bf16 into dead ws regions (xb@24MB, tf@104MB), rsum@120MB;
//    combine kernel (exact: no running max anywhere) writes ctxb before WO.
//  - gemm256 (XCD remap + counted-vmcnt pipelines), LN, prep unchanged.

typedef float  floatx2  __attribute__((ext_vector_type(2)));
typedef float  floatx4  __attribute__((ext_vector_type(4)));
typedef float  floatx16 __attribute__((ext_vector_type(16)));
typedef short  shortx8  __attribute__((ext_vector_type(8)));
typedef short  shortx4  __attribute__((ext_vector_type(4)));
typedef int    intx4    __attribute__((ext_vector_type(4)));
typedef unsigned uintx2 __attribute__((ext_vector_type(2)));

__device__ __forceinline__ short f2bs(float f) {  // fp32 -> bf16 bits (RTNE)
    union { float f; unsigned u; } a; a.f = f;
    unsigned r = a.u + 0x7fffu + ((a.u >> 16) & 1u);
    return (short)(r >> 16);
}

__device__ __forceinline__ float fexp2(float x) {
#if __has_builtin(__builtin_amdgcn_exp2f)
    return __builtin_amdgcn_exp2f(x);
#else
    return __expf(0.6931471805599453f * x);
#endif
}

// swap: a's hi-32-lanes <-> b's lo-32-lanes (v_permlane32_swap_b32)
__device__ __forceinline__ void lane32swap(unsigned& a, unsigned& b) {
#if __has_builtin(__builtin_amdgcn_permlane32_swap)
    uintx2 r = __builtin_amdgcn_permlane32_swap(a, b, false, false);
    a = r[0]; b = r[1];
#else
    int hl = (threadIdx.x & 63) >> 5;
    unsigned ta = (unsigned)__shfl_xor((int)a, 32);
    unsigned tb = (unsigned)__shfl_xor((int)b, 32);
    unsigned na = hl ? tb : a;
    unsigned nb = hl ? b : ta;
    a = na; b = nb;
#endif
}

__device__ __forceinline__ void gload16(const short* g, short* l) {
    __builtin_amdgcn_global_load_lds(
        (const __attribute__((address_space(1))) void*)g,
        (__attribute__((address_space(3))) void*)l,
        16, 0, 0);
}

#define WAITV(n) asm volatile("s_waitcnt vmcnt(" #n ")" ::: "memory")
#define FENCE    asm volatile("" ::: "memory")

// ---------------- fused prep: 6 weight transposes + x cast, one launch ----------------
__device__ __forceinline__ void trans_tile(const float* __restrict__ in,
                                           short* __restrict__ out,
                                           int N, int K, int k0, int n0,
                                           short (*t)[68]) {
    const int tid = threadIdx.x;
    const int r = tid >> 4, c4 = (tid & 15) * 4;
#pragma unroll
    for (int i = 0; i < 4; ++i) {
        int k = r + i * 16;
        floatx4 v = *(const floatx4*)(in + (size_t)(k0 + k) * N + n0 + c4);
        shortx4 s;
#pragma unroll
        for (int j = 0; j < 4; ++j) s[j] = f2bs(v[j]);
        *(shortx4*)(&t[k][c4]) = s;
    }
    __syncthreads();
#pragma unroll
    for (int i = 0; i < 4; ++i) {
        int n = r + i * 16;
        shortx4 s;
#pragma unroll
        for (int j = 0; j < 4; ++j) s[j] = t[c4 + j][n];
        *(shortx4*)(out + (size_t)(n0 + n) * K + k0 + c4) = s;
    }
}

__global__ __launch_bounds__(256) void prep_kernel(
    const float* __restrict__ wq, const float* __restrict__ wk,
    const float* __restrict__ wv, const float* __restrict__ wo,
    const float* __restrict__ w1, const float* __restrict__ w2,
    const float* __restrict__ x,
    short* wqt, short* wkt, short* wvt, short* wot,
    short* w1t, short* w2t, short* xb)
{
    __shared__ __align__(16) short t[64][68];
    const int bid = blockIdx.x;
    if (bid < 1024) {
        const int widx = bid >> 8, local = bid & 255;
        const float* in = widx == 0 ? wq : widx == 1 ? wk : widx == 2 ? wv : wo;
        short* out = widx == 0 ? wqt : widx == 1 ? wkt : widx == 2 ? wvt : wot;
        trans_tile(in, out, 1024, 1024, (local & 15) * 64, (local >> 4) * 64, t);
    } else if (bid < 2048) {
        const int local = bid - 1024;
        trans_tile(w1, w1t, 4096, 1024, (local & 15) * 64, (local >> 4) * 64, t);
    } else if (bid < 3072) {
        const int local = bid - 2048;
        trans_tile(w2, w2t, 1024, 4096, (local & 63) * 64, (local >> 6) * 64, t);
    } else {
        const int local = bid - 3072;
#pragma unroll
        for (int j = 0; j < 4; ++j) {
            int i = local * 1024 + j * 256 + threadIdx.x;
            floatx4 v = *(const floatx4*)(x + (size_t)i * 4);
            shortx4 o;
            o[0] = f2bs(v[0]); o[1] = f2bs(v[1]); o[2] = f2bs(v[2]); o[3] = f2bs(v[3]);
            *(shortx4*)(xb + (size_t)i * 4) = o;
        }
    }
}

// ---------------- GEMM: 256xBN tile, BK=64, 8 waves, counted-vmcnt pipeline ----------
// C[M,N] = A[M,K](bf16) * Bt[N,K]^T(bf16).
// BN=256: LDS 128KB (2 buf), 4 phases/K-tile, stage order A0,B0,B1,A1, WAITV(4).
// BN=128: LDS 144KB (3 buf), 2 phases/K-tile, prefetch 2 tiles ahead, WAITV(8).
// XCD remap: h=(bx+by*gridX); xcd=h&7 owns 4 consecutive by-panels -> A-panel L2
// reuse within an XCD (requires gridY==32, total%8==0; bijective).
// XOR swizzle: 16B-unit u_phys = u_log ^ ((row>>1)&7); applied on global SOURCE col
// (global_load_lds dest stays linear) and on ds_read addresses -> conflict-free reads.
// EPI 1: +bias, relu, bf16 (FFN1)   EPI 2: +resf fp32 (WO)
// EPI 3: +bias+resf fp32 (FFN2)     EPI 5: fused QKV scatter
template<int EPI, int BN>
__global__ __launch_bounds__(512, 2) void gemm256(
    const short* __restrict__ A, const short* __restrict__ Bt, const int K, const int N,
    short* __restrict__ outb, float* __restrict__ outf,
    const float* __restrict__ bias, const float* __restrict__ resf)
{
    constexpr int BUFSZ = 16384 + BN * 64;   // shorts per buffer (A 256x64 + B BNx64)
    constexpr int NF = BN / 64;              // acc N-frags per wave
    constexpr int NBUF = (BN == 128) ? 3 : 2;
    __shared__ __align__(16) short Ls[NBUF * BUFSZ];
    const int tid = threadIdx.x;
    const int w = tid >> 6, lane = tid & 63;
    const int quad = lane >> 4, l16 = lane & 15;
    const int wm = w >> 2, wn = w & 3;          // 2 x 4 wave grid
    // XCD-aware remap: xcd = h&7 gets by in [xcd*4, xcd*4+4), bx sweeps all.
    const int hsw = blockIdx.x + blockIdx.y * gridDim.x;
    const int vv = hsw >> 3;
    const int by = (hsw & 7) * 4 + (vv & 3);
    const int bx = vv >> 2;

    // staging source (per-lane, col pre-swizzled so linear LDS dest = swizzled layout)
    const int srow = w * 16 + (lane >> 3);
    const int uc0 = ((lane & 7) ^ ((lane >> 4) & 7)) * 8;          // gi=0
    const int uc1 = ((lane & 7) ^ (((lane >> 4) + 4) & 7)) * 8;    // gi=1
    const short* aS0 = A  + (size_t)(by * 256 + srow) * K + uc0;
    const short* aS1 = A  + (size_t)(by * 256 + srow + 8) * K + uc1;
    const short* bS0 = Bt + (size_t)(bx * BN + srow) * K + uc0;
    const short* bS1 = Bt + (size_t)(bx * BN + srow + 8) * K + uc1;
    const size_t hK = (size_t)128 * K;          // +128 rows
    const int wsl = w * 1024;                   // wave's staging slice (shorts)

    // ds_read offsets (shorts). rswz constant per thread: row bases are mult of 16.
    const int rswz = (l16 >> 1) & 7;
    const int ru0 = (quad ^ rswz) * 8;          // ks=0 swizzled unit
    const int ru1 = ((4 + quad) ^ rswz) * 8;    // ks=1 swizzled unit
    const int aRd = (wm * 64 + l16) * 64;
    const int bRd = (wn * 32 + l16) * 64;

    floatx4 acc[8][NF] = {};
    shortx8 af[4][2], blo[2][2], bhi[2][2];

#define S_A0(buf, kc) { short* p = Ls + (buf) * BUFSZ + wsl;         gload16(aS0 + (kc), p);      gload16(aS1 + (kc), p + 512);      FENCE; }
#define S_A1(buf, kc) { short* p = Ls + (buf) * BUFSZ + 8192 + wsl;  gload16(aS0 + hK + (kc), p); gload16(aS1 + hK + (kc), p + 512); FENCE; }
#define S_B0(buf, kc) { short* p = Ls + (buf) * BUFSZ + 16384 + wsl; gload16(bS0 + (kc), p);      gload16(bS1 + (kc), p + 512);      FENCE; }
#define S_B1(buf, kc) { short* p = Ls + (buf) * BUFSZ + 24576 + wsl; gload16(bS0 + hK + (kc), p); gload16(bS1 + hK + (kc), p + 512); FENCE; }
#define MF(a, b, c) c = __builtin_amdgcn_mfma_f32_16x16x32_bf16(a, b, c, 0, 0, 0)

#define RD_ALO(Ab) {                                                      \
_Pragma("unroll")                                                         \
        for (int mf = 0; mf < 4; ++mf) {                                  \
            af[mf][0] = *(const shortx8*)((Ab) + aRd + mf * 1024 + ru0);  \
            af[mf][1] = *(const shortx8*)((Ab) + aRd + mf * 1024 + ru1);  \
        } }
#define RD_AHI(Ab) {                                                      \
_Pragma("unroll")                                                         \
        for (int mf = 0; mf < 4; ++mf) {                                  \
            af[mf][0] = *(const shortx8*)((Ab) + aRd + 8192 + mf * 1024 + ru0); \
            af[mf][1] = *(const shortx8*)((Ab) + aRd + 8192 + mf * 1024 + ru1); \
        } }
#define RD_BLO(Bb) {                                                      \
_Pragma("unroll")                                                         \
        for (int nf = 0; nf < 2; ++nf) {                                  \
            blo[nf][0] = *(const shortx8*)((Bb) + bRd + nf * 1024 + ru0); \
            blo[nf][1] = *(const shortx8*)((Bb) + bRd + nf * 1024 + ru1); \
        } }
#define MFMA_LO { __builtin_amdgcn_s_setprio(1);                          \
_Pragma("unroll")                                                         \
        for (int mf = 0; mf < 4; ++mf)                                    \
_Pragma("unroll")                                                         \
            for (int nf = 0; nf < 2; ++nf) {                              \
                MF(af[mf][0], blo[nf][0], acc[mf][nf]);                   \
                MF(af[mf][1], blo[nf][1], acc[mf][nf]);                   \
            }                                                             \
        __builtin_amdgcn_s_setprio(0); }
#define MFMA_HI { __builtin_amdgcn_s_setprio(1);                          \
_Pragma("unroll")                                                         \
        for (int mf = 0; mf < 4; ++mf)                                    \
_Pragma("unroll")                                                         \
            for (int nf = 0; nf < 2; ++nf) {                              \
                MF(af[mf][0], blo[nf][0], acc[4 + mf][nf]);               \
                MF(af[mf][1], blo[nf][1], acc[4 + mf][nf]);               \
            }                                                             \
        __builtin_amdgcn_s_setprio(0); }

    const int NT = K >> 6;

    if constexpr (BN == 256) {
        // prologue: stage tile 0 in consumption order
        S_A0(0, 0) S_B0(0, 0) S_B1(0, 0) S_A1(0, 0)
        for (int t = 0; t < NT - 1; ++t) {
            const int rb = t & 1, wbuf = rb ^ 1, kc = (t + 1) * 64;
            const short* Ab = Ls + rb * BUFSZ;
            const short* Bb = Ab + 16384;
            // ---- P1: q0 = A-lo x B-lo ----
            WAITV(4); __builtin_amdgcn_s_barrier(); FENCE;
            RD_ALO(Ab) RD_BLO(Bb)
            S_A0(wbuf, kc)
            MFMA_LO
            // ---- P2: q1 = A-lo x B-hi ----
            WAITV(4); __builtin_amdgcn_s_barrier(); FENCE;
#pragma unroll
            for (int nf = 0; nf < 2; ++nf) {
                bhi[nf][0] = *(const shortx8*)(Bb + bRd + 8192 + nf * 1024 + ru0);
                bhi[nf][1] = *(const shortx8*)(Bb + bRd + 8192 + nf * 1024 + ru1);
            }
            S_B0(wbuf, kc)
            __builtin_amdgcn_s_setprio(1);
#pragma unroll
            for (int mf = 0; mf < 4; ++mf)
#pragma unroll
                for (int nf = 0; nf < 2; ++nf) {
                    MF(af[mf][0], bhi[nf][0], acc[mf][2 + nf]);
                    MF(af[mf][1], bhi[nf][1], acc[mf][2 + nf]);
                }
            __builtin_amdgcn_s_setprio(0);
            // ---- P3: q2 = A-hi x B-lo ----
            WAITV(4); __builtin_amdgcn_s_barrier(); FENCE;
            RD_AHI(Ab)
            S_B1(wbuf, kc)
            MFMA_HI
            // ---- P4: q3 = A-hi x B-hi ----
            S_A1(wbuf, kc)
            __builtin_amdgcn_s_setprio(1);
#pragma unroll
            for (int mf = 0; mf < 4; ++mf)
#pragma unroll
                for (int nf = 0; nf < 2; ++nf) {
                    MF(af[mf][0], bhi[nf][0], acc[4 + mf][2 + nf]);
                    MF(af[mf][1], bhi[nf][1], acc[4 + mf][2 + nf]);
                }
            __builtin_amdgcn_s_setprio(0);
        }
        // ---- tail tile ----
        {
            const int rb = (NT - 1) & 1;
            const short* Ab = Ls + rb * BUFSZ;
            const short* Bb = Ab + 16384;
            WAITV(4); __builtin_amdgcn_s_barrier(); FENCE;
            RD_ALO(Ab) RD_BLO(Bb)
            MFMA_LO
            WAITV(2); __builtin_amdgcn_s_barrier(); FENCE;
#pragma unroll
            for (int nf = 0; nf < 2; ++nf) {
                bhi[nf][0] = *(const shortx8*)(Bb + bRd + 8192 + nf * 1024 + ru0);
                bhi[nf][1] = *(const shortx8*)(Bb + bRd + 8192 + nf * 1024 + ru1);
            }
            __builtin_amdgcn_s_setprio(1);
#pragma unroll
            for (int mf = 0; mf < 4; ++mf)
#pragma unroll
                for (int nf = 0; nf < 2; ++nf) {
                    MF(af[mf][0], bhi[nf][0], acc[mf][2 + nf]);
                    MF(af[mf][1], bhi[nf][1], acc[mf][2 + nf]);
                }
            __builtin_amdgcn_s_setprio(0);
            WAITV(0); __builtin_amdgcn_s_barrier(); FENCE;
            RD_AHI(Ab)
            __builtin_amdgcn_s_setprio(1);
#pragma unroll
            for (int mf = 0; mf < 4; ++mf)
#pragma unroll
                for (int nf = 0; nf < 2; ++nf) {
                    MF(af[mf][0], blo[nf][0], acc[4 + mf][nf]);
                    MF(af[mf][1], blo[nf][1], acc[4 + mf][nf]);
                    MF(af[mf][0], bhi[nf][0], acc[4 + mf][2 + nf]);
                    MF(af[mf][1], bhi[nf][1], acc[4 + mf][2 + nf]);
                }
            __builtin_amdgcn_s_setprio(0);
        }
    } else {
        // -------- BN == 128: 2-phase, 3-buffer, prefetch 2 K-tiles ahead --------
        S_A0(0, 0) S_B0(0, 0) S_A1(0, 0)
        S_A0(1, 64) S_B0(1, 64) S_A1(1, 64)
        for (int t = 0; t < NT - 2; ++t) {
            const int rb = t % 3, pb = (t + 2) % 3, kc = (t + 2) * 64;
            const short* Ab = Ls + rb * BUFSZ;
            const short* Bb = Ab + 16384;
            // ---- P1: A-lo x B ----
            WAITV(8); __builtin_amdgcn_s_barrier(); FENCE;
            RD_ALO(Ab) RD_BLO(Bb)
            S_A0(pb, kc)
            MFMA_LO
            // ---- P2: A-hi x B ----
            WAITV(8); __builtin_amdgcn_s_barrier(); FENCE;
            RD_AHI(Ab)
            S_B0(pb, kc) S_A1(pb, kc)
            MFMA_HI
        }
        // ---- tile NT-2 (no staging; drains 8 -> 6) ----
        {
            const int rb = (NT - 2) % 3;
            const short* Ab = Ls + rb * BUFSZ;
            const short* Bb = Ab + 16384;
            WAITV(8); __builtin_amdgcn_s_barrier(); FENCE;
            RD_ALO(Ab) RD_BLO(Bb)
            MFMA_LO
            WAITV(6); __builtin_amdgcn_s_barrier(); FENCE;
            RD_AHI(Ab)
            MFMA_HI
        }
        // ---- tile NT-1 (drains 2 -> 0) ----
        {
            const int rb = (NT - 1) % 3;
            const short* Ab = Ls + rb * BUFSZ;
            const short* Bb = Ab + 16384;
            WAITV(2); __builtin_amdgcn_s_barrier(); FENCE;
            RD_ALO(Ab) RD_BLO(Bb)
            MFMA_LO
            WAITV(0); __builtin_amdgcn_s_barrier(); FENCE;
            RD_AHI(Ab)
            MFMA_HI
        }
    }

    // ---- epilogue ----
#pragma unroll
    for (int mf = 0; mf < 8; ++mf) {
        const int grow0 = by * 256 + (mf >> 2) * 128 + wm * 64 + (mf & 3) * 16 + quad * 4;
#pragma unroll
        for (int nf = 0; nf < NF; ++nf) {
            int gcol;
            if constexpr (BN == 256)
                gcol = bx * 256 + (nf >> 1) * 128 + wn * 32 + (nf & 1) * 16 + l16;
            else
                gcol = bx * 128 + wn * 32 + nf * 16 + l16;
            const floatx4 a = acc[mf][nf];
            if constexpr (EPI == 5) {
                const int slice = gcol >> 10, c = gcol & 1023;
                const int hh = c >> 6, d = c & 63;
                const int b = grow0 >> 11, s0 = grow0 & 2047;
                if (slice == 2) {
                    short* vt = outb + ((size_t)16 << 20);
                    shortx4 pkv;
#pragma unroll
                    for (int r = 0; r < 4; ++r) pkv[r] = f2bs(a[r]);
                    *(shortx4*)(vt + ((size_t)((b * 16 + hh) * 64 + d)) * 2048 + s0) = pkv;
                } else {
                    short* dst = slice ? (outb + ((size_t)8 << 20)) : outb;
                    // Q scale folds 1/sqrt(dk) AND log2(e) so softmax uses raw exp2
                    float sc = slice ? 1.f : 0.125f * 1.4426950408889634f;
#pragma unroll
                    for (int r = 0; r < 4; ++r)
                        dst[(((size_t)(b * 16 + hh)) * 2048 + (s0 + r)) * 64 + d] =
                            f2bs(a[r] * sc);
                }
            } else if constexpr (EPI == 1) {
                const float bv = bias[gcol];
#pragma unroll
                for (int r = 0; r < 4; ++r) {
                    float v = fmaxf(a[r] + bv, 0.f);
                    outb[(size_t)(grow0 + r) * N + gcol] = f2bs(v);
                }
            } else if constexpr (EPI == 2) {
#pragma unroll
                for (int r = 0; r < 4; ++r)
                    outf[(size_t)(grow0 + r) * N + gcol] =
                        a[r] + resf[(size_t)(grow0 + r) * N + gcol];
            } else if constexpr (EPI == 3) {
                const float bv = bias[gcol];
#pragma unroll
                for (int r = 0; r < 4; ++r)
                    outf[(size_t)(grow0 + r) * N + gcol] =
                        a[r] + bv + resf[(size_t)(grow0 + r) * N + gcol];
            }
        }
    }
#undef S_A0
#undef S_A1
#undef S_B0
#undef S_B1
#undef MF
#undef RD_ALO
#undef RD_AHI
#undef RD_BLO
#undef MFMA_LO
#undef MFMA_HI
}

// ---------------- LayerNorm over D=1024, one block per row ----------------
__global__ __launch_bounds__(256) void ln_kernel(
    const float* __restrict__ in, float* __restrict__ outf, short* __restrict__ outb,
    const float* __restrict__ g, const float* __restrict__ be, int writeB)
{
    __shared__ float red[8];
    const int row = blockIdx.x, tid = threadIdx.x;
    const float* p = in + (size_t)row * 1024;
    floatx4 v = *(const floatx4*)(p + tid * 4);
    float s = v[0] + v[1] + v[2] + v[3];
    float q = v[0] * v[0] + v[1] * v[1] + v[2] * v[2] + v[3] * v[3];
#pragma unroll
    for (int off = 32; off; off >>= 1) {
        s += __shfl_xor(s, off);
        q += __shfl_xor(q, off);
    }
    int w = tid >> 6, lane = tid & 63;
    if (lane == 0) { red[w] = s; red[4 + w] = q; }
    __syncthreads();
    s = red[0] + red[1] + red[2] + red[3];
    q = red[4] + red[5] + red[6] + red[7];
    float mean = s * (1.f / 1024.f);
    float var = q * (1.f / 1024.f) - mean * mean;
    float rs = rsqrtf(var + 1e-5f);
    floatx4 gv = *(const floatx4*)(g + tid * 4);
    floatx4 bv = *(const floatx4*)(be + tid * 4);
    floatx4 o4;
#pragma unroll
    for (int i = 0; i < 4; ++i) o4[i] = (v[i] - mean) * rs * gv[i] + bv[i];
    *(floatx4*)(outf + (size_t)row * 1024 + tid * 4) = o4;
    if (writeB) {
        shortx4 ob;
#pragma unroll
        for (int i = 0; i < 4; ++i) ob[i] = f2bs(o4[i]);
        *(shortx4*)(outb + (size_t)row * 1024 + tid * 4) = ob;
    }
}

// ---------------- Flash attention: kv-split x2, 64 q-rows/wave, 4 blocks/CU --------
// Q,K: [B*H][2048][64] bf16 (Q pre-scaled by log2e/8). Vt: [B*H][64][2048] bf16.
// Grid (64,16): bx = bh (head's K/V pinned to XCD bh%8); by: qt=by>>1 (256-row
// q-tile), kvh=by&1 (kv half: 16 of 32 kv-tiles). 1024 blocks = 4/CU = 16 waves/CU
// AND 64 q-rows/wave (qg=0,1) -> halved LDS/FLOP with full occupancy.
// No running max anywhere (P = exp2(s)), so halves combine exactly in
// combine_kernel: O = (O0+O1)/(r0+r1). Partials: bf16 O + fp32 rsum.
// K tile [64][64] + V tile [64][64] per buffer (16KB), double-buffered;
// unit_phys = unit_log ^ (row&7) via pre-swizzled global source.
__global__ __launch_bounds__(256, 4) void attn_kernel(
    const short* __restrict__ Q, const short* __restrict__ K,
    const short* __restrict__ Vt, short* __restrict__ oPA,
    short* __restrict__ oPB, float* __restrict__ rsP)
{
    __shared__ __align__(16) short Ls[18432];  // 36 KB; loop 32 KB (2 bufs); epi 256x72
    const int tid = threadIdx.x;
    const int bh = blockIdx.x;
    const int qt = blockIdx.y >> 1, kvh = blockIdx.y & 1;
    const int q0 = qt * 256;
    const int w = tid >> 6, lane = tid & 63, l31 = lane & 31, hl = lane >> 5;
    const size_t sb = (size_t)bh * 2048 * 64;
    const int kvbase = kvh * 1024;

    shortx8 qf[2][4];
#pragma unroll
    for (int qg = 0; qg < 2; ++qg)
#pragma unroll
        for (int ks = 0; ks < 4; ++ks)
            qf[qg][ks] = *(const shortx8*)(Q + sb + (size_t)(q0 + w * 64 + qg * 32 + l31) * 64 + ks * 16 + hl * 8);

    // staging: sweep j covers rows j*32 + w*8 + (lane>>3); phys unit = lane&7;
    // source logical unit = (lane&7) ^ (row&7), row&7 = lane>>3.
    const int srow = w * 8 + (lane >> 3);
    const int sunit = ((lane & 7) ^ (lane >> 3)) * 8;
    const short* kSrc = K + sb + (size_t)srow * 64 + sunit;        // + kv0*64 + j*2048
    const short* vSrc = Vt + sb + (size_t)srow * 2048 + sunit;     // + kv0 + j*65536
    const int sdst = w * 512;                                      // + buf*8192 + j*2048

    // read-side swizzle component
    const int kx = l31 & 7;

    floatx16 o[2][2] = {};                 // [qg][mtd]
    floatx2 rs0A = {0.f, 0.f}, rs0B = {0.f, 0.f};
    floatx2 rs1A = {0.f, 0.f}, rs1B = {0.f, 0.f};
    const floatx16 z = {};

#define STAGE(buf, kv0) { \
    short* kb = Ls + (buf) * 8192 + sdst; \
    gload16(kSrc + (size_t)(kv0) * 64, kb); \
    gload16(kSrc + (size_t)(kv0) * 64 + 2048, kb + 2048); \
    gload16(vSrc + (kv0), kb + 4096); \
    gload16(vSrc + (kv0) + 65536, kb + 6144); \
    FENCE; }

#define LD_AK(B, mt, ks) (*(const shortx8*)((B) + ((mt) * 32 + l31) * 64 + ((((ks) * 2 + hl) ^ kx)) * 8))
#define LD_AV(B, mtd, mt, ksl) (*(const shortx8*)((B) + 4096 + ((mtd) * 32 + l31) * 64 + ((((mt) * 4 + (ksl) * 2 + hl) ^ kx)) * 8))
#define MFA(a, b, c) __builtin_amdgcn_mfma_f32_32x32x16_bf16(a, b, c, 0, 0, 0)

    STAGE(0, kvbase)

    for (int kt = 0; kt < 16; ++kt) {
        WAITV(0);                       // tile kt staged (issued 1 compute phase ago)
        __builtin_amdgcn_s_barrier();   // all waves: loads drained + prev reads done
        FENCE;
        if (kt < 15) STAGE((kt + 1) & 1, kvbase + (kt + 1) * 64)
        const short* B = Ls + (kt & 1) * 8192;

#pragma unroll
        for (int mt = 0; mt < 2; ++mt) {
            shortx8 ak[4], av[2][2];
#pragma unroll
            for (int ks = 0; ks < 4; ++ks) ak[ks] = LD_AK(B, mt, ks);
#pragma unroll
            for (int ksl = 0; ksl < 2; ++ksl)
#pragma unroll
                for (int mtd = 0; mtd < 2; ++mtd) av[ksl][mtd] = LD_AV(B, mtd, mt, ksl);
            floatx16 sc0, sc1;
            __builtin_amdgcn_s_setprio(1);
            sc0 = MFA(ak[0], qf[0][0], z);
            sc0 = MFA(ak[1], qf[0][1], sc0);
            sc0 = MFA(ak[2], qf[0][2], sc0);
            sc0 = MFA(ak[3], qf[0][3], sc0);
            sc1 = MFA(ak[0], qf[1][0], z);
            sc1 = MFA(ak[1], qf[1][1], sc1);
            sc1 = MFA(ak[2], qf[1][2], sc1);
            sc1 = MFA(ak[3], qf[1][3], sc1);
            __builtin_amdgcn_s_setprio(0);
#pragma unroll
            for (int qg = 0; qg < 2; ++qg) {
                const floatx16 sc = qg ? sc1 : sc0;
                // exp2 (log2e folded into Q), packed pairwise sum
                floatx2 ps2[8];
#pragma unroll
                for (int i = 0; i < 8; ++i) {
                    ps2[i][0] = fexp2(sc[2 * i]);
                    ps2[i][1] = fexp2(sc[2 * i + 1]);
                }
                if (qg == 0) {
#pragma unroll
                    for (int i = 0; i < 8; i += 2) { rs0A += ps2[i]; rs0B += ps2[i + 1]; }
                } else {
#pragma unroll
                    for (int i = 0; i < 8; i += 2) { rs1A += ps2[i]; rs1B += ps2[i + 1]; }
                }
                unsigned pk[8];
#pragma unroll
                for (int i = 0; i < 8; ++i) {
                    union { __hip_bfloat162 h; unsigned u; } cv;
                    cv.h = __float22bfloat162_rn(make_float2(ps2[i][0], ps2[i][1]));
                    pk[i] = cv.u;
                }
                // half-lane swaps: [pk0..pk3] = B-frag kv 0..15, [pk4..pk7] = kv 16..31
                lane32swap(pk[0], pk[2]);
                lane32swap(pk[1], pk[3]);
                lane32swap(pk[4], pk[6]);
                lane32swap(pk[5], pk[7]);
                __builtin_amdgcn_s_setprio(1);
#pragma unroll
                for (int ksl = 0; ksl < 2; ++ksl) {
                    union { unsigned i[4]; shortx8 s8; } fr;
                    fr.i[0] = pk[4 * ksl];     fr.i[1] = pk[4 * ksl + 1];
                    fr.i[2] = pk[4 * ksl + 2]; fr.i[3] = pk[4 * ksl + 3];
#pragma unroll
                    for (int mtd = 0; mtd < 2; ++mtd)
                        o[qg][mtd] = MFA(av[ksl][mtd], fr.s8, o[qg][mtd]);
                }
                __builtin_amdgcn_s_setprio(0);
            }
        }
    }
#undef STAGE
#undef LD_AK
#undef LD_AV
#undef MFA

    // per-row partial softmax denominators (no normalization here)
    float t0, t1;
    {
        float r0 = rs0A[0] + rs0A[1] + rs0B[0] + rs0B[1];
        t0 = r0 + __shfl_xor(r0, 32);
        float r1 = rs1A[0] + rs1A[1] + rs1B[0] + rs1B[1];
        t1 = r1 + __shfl_xor(r1, 32);
    }
    if (hl == 0) {
        float* rp = rsP + (size_t)kvh * 131072 + bh * 2048 + q0;
        rp[w * 64 + l31] = t0;
        rp[w * 64 + 32 + l31] = t1;
    }

    short* oP = kvh ? oPB : oPA;
    __syncthreads();
    short* O_lds = Ls;   // 256 rows x 72 shorts = 36 KB
#pragma unroll
    for (int qg = 0; qg < 2; ++qg) {
#pragma unroll
        for (int mtd = 0; mtd < 2; ++mtd)
#pragma unroll
            for (int g = 0; g < 4; ++g) {
                shortx4 p4;
#pragma unroll
                for (int r = 0; r < 4; ++r) p4[r] = f2bs(o[qg][mtd][4 * g + r]);
                *(shortx4*)(O_lds + (w * 64 + qg * 32 + l31) * 72 + mtd * 32 + g * 8 + hl * 4) = p4;
            }
    }
    __syncthreads();
    // dump unnormalized partial O: [bh][q][64] bf16
#pragma unroll
    for (int it = 0; it < 8; ++it) {
        int idx = it * 256 + tid;
        int q = idx >> 3, ch = idx & 7;
        shortx8 v = *(const shortx8*)(O_lds + q * 72 + ch * 8);
        *(shortx8*)(oP + sb + (size_t)(q0 + q) * 64 + ch * 8) = v;
    }
}

// ---------------- combine: ctx = (O0 + O1) / (r0 + r1), scatter to [B*S][1024] -----
__global__ __launch_bounds__(256) void combine_kernel(
    const short* __restrict__ oPA, const short* __restrict__ oPB,
    const float* __restrict__ rsP, short* __restrict__ ctx)
{
    const int gid = blockIdx.x * 256 + threadIdx.x;   // 1,048,576 threads
    const int row = gid >> 3, dg = (gid & 7) * 8;     // row in [0, 131072)
    const int bh = row >> 11, q = row & 2047;
    const float inv = 1.f / (rsP[row] + rsP[131072 + row]);
    shortx8 a = *(const shortx8*)(oPA + (size_t)row * 64 + dg);
    shortx8 b = *(const shortx8*)(oPB + (size_t)row * 64 + dg);
    shortx8 o;
#pragma unroll
    for (int i = 0; i < 8; ++i) {
        union { unsigned u; float f; } fa, fb;
        fa.u = ((unsigned)(unsigned short)a[i]) << 16;
        fb.u = ((unsigned)(unsigned short)b[i]) << 16;
        o[i] = f2bs((fa.f + fb.f) * inv);
    }
    const int bb = bh >> 4, head = bh & 15;
    *(shortx8*)(ctx + ((size_t)(bb * 2048 + q)) * 1024 + head * 64 + dg) = o;
}

// ---------------- launch ----------------
extern "C" void kernel_launch(void* const* d_in, const int* in_sizes, int n_in,
                              void* d_out, int out_size, void* d_ws, size_t ws_size,
                              hipStream_t stream) {
    const float* x   = (const float*)d_in[0];
    const float* wq  = (const float*)d_in[1];
    const float* wk  = (const float*)d_in[2];
    const float* wv  = (const float*)d_in[3];
    const float* wo  = (const float*)d_in[4];
    const float* w1  = (const float*)d_in[5];
    const float* b1  = (const float*)d_in[6];
    const float* w2  = (const float*)d_in[7];
    const float* b2  = (const float*)d_in[8];
    const float* g1p = (const float*)d_in[9];
    const float* be1 = (const float*)d_in[10];
    const float* g2p = (const float*)d_in[11];
    const float* be2 = (const float*)d_in[12];
    float* out = (float*)d_out;

    char* ws = (char*)d_ws;
    const size_t MB = 1ull << 20;
    short* wqt  = (short*)(ws + 0 * MB);
    short* wkt  = (short*)(ws + 2 * MB);
    short* wvt  = (short*)(ws + 4 * MB);
    short* wot  = (short*)(ws + 6 * MB);
    short* w1t  = (short*)(ws + 8 * MB);
    short* w2t  = (short*)(ws + 16 * MB);
    short* xb   = (short*)(ws + 24 * MB);
    short* Qb   = (short*)(ws + 40 * MB);   // K at +16MB, Vt at +32MB (EPI5 offsets)
    short* Kb   = (short*)(ws + 56 * MB);
    short* Vtg  = (short*)(ws + 72 * MB);
    short* ctxb = (short*)(ws + 88 * MB);
    float* tf   = (float*)(ws + 104 * MB);
    short* hb   = (short*)(ws + 136 * MB);
    short* f1b  = (short*)(ws + 40 * MB);   // reuses Qb..ctxb (dead by then)
    // attn partials (regions dead during attention):
    short* oPA  = (short*)(ws + 24 * MB);   // xb region (dead after QKV gemm)
    short* oPB  = (short*)(ws + 104 * MB);  // tf region (written later by WO)
    float* rsP  = (float*)(ws + 120 * MB);  // 1 MB, inside tf region

    prep_kernel<<<5120, 256, 0, stream>>>(wq, wk, wv, wo, w1, w2, x,
                                          wqt, wkt, wvt, wot, w1t, w2t, xb);

    gemm256<5, 128><<<dim3(24, 32), 512, 0, stream>>>(xb, wqt, 1024, 3072, Qb, nullptr, nullptr, nullptr);
    attn_kernel<<<dim3(64, 16), 256, 0, stream>>>(Qb, Kb, Vtg, oPA, oPB, rsP);
    combine_kernel<<<4096, 256, 0, stream>>>(oPA, oPB, rsP, ctxb);
    gemm256<2, 128><<<dim3(8, 32), 512, 0, stream>>>(ctxb, wot, 1024, 1024, nullptr, tf, nullptr, x);
    ln_kernel<<<8192, 256, 0, stream>>>(tf, tf, hb, g1p, be1, 1);
    gemm256<1, 256><<<dim3(16, 32), 512, 0, stream>>>(hb, w1t, 1024, 4096, f1b, nullptr, b1, nullptr);
    gemm256<3, 128><<<dim3(8, 32), 512, 0, stream>>>(f1b, w2t, 4096, 1024, nullptr, out, b2, tf);
    ln_kernel<<<8192, 256, 0, stream>>>(out, out, nullptr, g2p, be2, 0);
}

// Round 10
// 367.874 us; speedup vs baseline: 1.8809x; 1.8809x over previous
//
#include <hip/hip_runtime.h>
#include <hip/hip_bf16.h>

// MyTransformerEncoderBlock: B=4, S=2048, D=1024, H=16, dk=64, D_FF=4096
// Round 16:
//  - attn: revert kv-split (r8: launch_bounds(256,4) capped VGPR at 64 -> spill,
//    414us). Back to round-11 attn (32q/wave, 4 blocks/CU, dbuf KVBLK=64, 89.9us,
//    VGPR 52) with grid transposed to (64,16): blockId%8 = bh%8 pins each head's
//    q-tiles to one XCD (r7-validated: FETCH 139->27MB).
//  - FFN1: BN=256 2-buf -> BN=128 3-buf deep pipeline (grid (32,32) = 4 exact
//    rounds/CU), same structure as QKV/FFN2 which outgrew the 2-deep variants.
//  - gemm256 (XCD remap + counted-vmcnt), LN, prep unchanged.

typedef float  floatx2  __attribute__((ext_vector_type(2)));
typedef float  floatx4  __attribute__((ext_vector_type(4)));
typedef float  floatx16 __attribute__((ext_vector_type(16)));
typedef short  shortx8  __attribute__((ext_vector_type(8)));
typedef short  shortx4  __attribute__((ext_vector_type(4)));
typedef int    intx4    __attribute__((ext_vector_type(4)));
typedef unsigned uintx2 __attribute__((ext_vector_type(2)));

__device__ __forceinline__ short f2bs(float f) {  // fp32 -> bf16 bits (RTNE)
    union { float f; unsigned u; } a; a.f = f;
    unsigned r = a.u + 0x7fffu + ((a.u >> 16) & 1u);
    return (short)(r >> 16);
}

__device__ __forceinline__ float fexp2(float x) {
#if __has_builtin(__builtin_amdgcn_exp2f)
    return __builtin_amdgcn_exp2f(x);
#else
    return __expf(0.6931471805599453f * x);
#endif
}

// swap: a's hi-32-lanes <-> b's lo-32-lanes (v_permlane32_swap_b32)
__device__ __forceinline__ void lane32swap(unsigned& a, unsigned& b) {
#if __has_builtin(__builtin_amdgcn_permlane32_swap)
    uintx2 r = __builtin_amdgcn_permlane32_swap(a, b, false, false);
    a = r[0]; b = r[1];
#else
    int hl = (threadIdx.x & 63) >> 5;
    unsigned ta = (unsigned)__shfl_xor((int)a, 32);
    unsigned tb = (unsigned)__shfl_xor((int)b, 32);
    unsigned na = hl ? tb : a;
    unsigned nb = hl ? b : ta;
    a = na; b = nb;
#endif
}

__device__ __forceinline__ void gload16(const short* g, short* l) {
    __builtin_amdgcn_global_load_lds(
        (const __attribute__((address_space(1))) void*)g,
        (__attribute__((address_space(3))) void*)l,
        16, 0, 0);
}

#define WAITV(n) asm volatile("s_waitcnt vmcnt(" #n ")" ::: "memory")
#define FENCE    asm volatile("" ::: "memory")

// ---------------- fused prep: 6 weight transposes + x cast, one launch ----------------
__device__ __forceinline__ void trans_tile(const float* __restrict__ in,
                                           short* __restrict__ out,
                                           int N, int K, int k0, int n0,
                                           short (*t)[68]) {
    const int tid = threadIdx.x;
    const int r = tid >> 4, c4 = (tid & 15) * 4;
#pragma unroll
    for (int i = 0; i < 4; ++i) {
        int k = r + i * 16;
        floatx4 v = *(const floatx4*)(in + (size_t)(k0 + k) * N + n0 + c4);
        shortx4 s;
#pragma unroll
        for (int j = 0; j < 4; ++j) s[j] = f2bs(v[j]);
        *(shortx4*)(&t[k][c4]) = s;
    }
    __syncthreads();
#pragma unroll
    for (int i = 0; i < 4; ++i) {
        int n = r + i * 16;
        shortx4 s;
#pragma unroll
        for (int j = 0; j < 4; ++j) s[j] = t[c4 + j][n];
        *(shortx4*)(out + (size_t)(n0 + n) * K + k0 + c4) = s;
    }
}

__global__ __launch_bounds__(256) void prep_kernel(
    const float* __restrict__ wq, const float* __restrict__ wk,
    const float* __restrict__ wv, const float* __restrict__ wo,
    const float* __restrict__ w1, const float* __restrict__ w2,
    const float* __restrict__ x,
    short* wqt, short* wkt, short* wvt, short* wot,
    short* w1t, short* w2t, short* xb)
{
    __shared__ __align__(16) short t[64][68];
    const int bid = blockIdx.x;
    if (bid < 1024) {
        const int widx = bid >> 8, local = bid & 255;
        const float* in = widx == 0 ? wq : widx == 1 ? wk : widx == 2 ? wv : wo;
        short* out = widx == 0 ? wqt : widx == 1 ? wkt : widx == 2 ? wvt : wot;
        trans_tile(in, out, 1024, 1024, (local & 15) * 64, (local >> 4) * 64, t);
    } else if (bid < 2048) {
        const int local = bid - 1024;
        trans_tile(w1, w1t, 4096, 1024, (local & 15) * 64, (local >> 4) * 64, t);
    } else if (bid < 3072) {
        const int local = bid - 2048;
        trans_tile(w2, w2t, 1024, 4096, (local & 63) * 64, (local >> 6) * 64, t);
    } else {
        const int local = bid - 3072;
#pragma unroll
        for (int j = 0; j < 4; ++j) {
            int i = local * 1024 + j * 256 + threadIdx.x;
            floatx4 v = *(const floatx4*)(x + (size_t)i * 4);
            shortx4 o;
            o[0] = f2bs(v[0]); o[1] = f2bs(v[1]); o[2] = f2bs(v[2]); o[3] = f2bs(v[3]);
            *(shortx4*)(xb + (size_t)i * 4) = o;
        }
    }
}

// ---------------- GEMM: 256xBN tile, BK=64, 8 waves, counted-vmcnt pipeline ----------
// C[M,N] = A[M,K](bf16) * Bt[N,K]^T(bf16).
// BN=256: LDS 128KB (2 buf), 4 phases/K-tile, stage order A0,B0,B1,A1, WAITV(4).
// BN=128: LDS 144KB (3 buf), 2 phases/K-tile, prefetch 2 tiles ahead, WAITV(8).
// XCD remap: h=(bx+by*gridX); xcd=h&7 owns 4 consecutive by-panels -> A-panel L2
// reuse within an XCD (requires gridY==32, total%8==0; bijective).
// XOR swizzle: 16B-unit u_phys = u_log ^ ((row>>1)&7); applied on global SOURCE col
// (global_load_lds dest stays linear) and on ds_read addresses -> conflict-free reads.
// EPI 1: +bias, relu, bf16 (FFN1)   EPI 2: +resf fp32 (WO)
// EPI 3: +bias+resf fp32 (FFN2)     EPI 5: fused QKV scatter
template<int EPI, int BN>
__global__ __launch_bounds__(512, 2) void gemm256(
    const short* __restrict__ A, const short* __restrict__ Bt, const int K, const int N,
    short* __restrict__ outb, float* __restrict__ outf,
    const float* __restrict__ bias, const float* __restrict__ resf)
{
    constexpr int BUFSZ = 16384 + BN * 64;   // shorts per buffer (A 256x64 + B BNx64)
    constexpr int NF = BN / 64;              // acc N-frags per wave
    constexpr int NBUF = (BN == 128) ? 3 : 2;
    __shared__ __align__(16) short Ls[NBUF * BUFSZ];
    const int tid = threadIdx.x;
    const int w = tid >> 6, lane = tid & 63;
    const int quad = lane >> 4, l16 = lane & 15;
    const int wm = w >> 2, wn = w & 3;          // 2 x 4 wave grid
    // XCD-aware remap: xcd = h&7 gets by in [xcd*4, xcd*4+4), bx sweeps all.
    const int hsw = blockIdx.x + blockIdx.y * gridDim.x;
    const int vv = hsw >> 3;
    const int by = (hsw & 7) * 4 + (vv & 3);
    const int bx = vv >> 2;

    // staging source (per-lane, col pre-swizzled so linear LDS dest = swizzled layout)
    const int srow = w * 16 + (lane >> 3);
    const int uc0 = ((lane & 7) ^ ((lane >> 4) & 7)) * 8;          // gi=0
    const int uc1 = ((lane & 7) ^ (((lane >> 4) + 4) & 7)) * 8;    // gi=1
    const short* aS0 = A  + (size_t)(by * 256 + srow) * K + uc0;
    const short* aS1 = A  + (size_t)(by * 256 + srow + 8) * K + uc1;
    const short* bS0 = Bt + (size_t)(bx * BN + srow) * K + uc0;
    const short* bS1 = Bt + (size_t)(bx * BN + srow + 8) * K + uc1;
    const size_t hK = (size_t)128 * K;          // +128 rows
    const int wsl = w * 1024;                   // wave's staging slice (shorts)

    // ds_read offsets (shorts). rswz constant per thread: row bases are mult of 16.
    const int rswz = (l16 >> 1) & 7;
    const int ru0 = (quad ^ rswz) * 8;          // ks=0 swizzled unit
    const int ru1 = ((4 + quad) ^ rswz) * 8;    // ks=1 swizzled unit
    const int aRd = (wm * 64 + l16) * 64;
    const int bRd = (wn * 32 + l16) * 64;

    floatx4 acc[8][NF] = {};
    shortx8 af[4][2], blo[2][2], bhi[2][2];

#define S_A0(buf, kc) { short* p = Ls + (buf) * BUFSZ + wsl;         gload16(aS0 + (kc), p);      gload16(aS1 + (kc), p + 512);      FENCE; }
#define S_A1(buf, kc) { short* p = Ls + (buf) * BUFSZ + 8192 + wsl;  gload16(aS0 + hK + (kc), p); gload16(aS1 + hK + (kc), p + 512); FENCE; }
#define S_B0(buf, kc) { short* p = Ls + (buf) * BUFSZ + 16384 + wsl; gload16(bS0 + (kc), p);      gload16(bS1 + (kc), p + 512);      FENCE; }
#define S_B1(buf, kc) { short* p = Ls + (buf) * BUFSZ + 24576 + wsl; gload16(bS0 + hK + (kc), p); gload16(bS1 + hK + (kc), p + 512); FENCE; }
#define MF(a, b, c) c = __builtin_amdgcn_mfma_f32_16x16x32_bf16(a, b, c, 0, 0, 0)

#define RD_ALO(Ab) {                                                      \
_Pragma("unroll")                                                         \
        for (int mf = 0; mf < 4; ++mf) {                                  \
            af[mf][0] = *(const shortx8*)((Ab) + aRd + mf * 1024 + ru0);  \
            af[mf][1] = *(const shortx8*)((Ab) + aRd + mf * 1024 + ru1);  \
        } }
#define RD_AHI(Ab) {                                                      \
_Pragma("unroll")                                                         \
        for (int mf = 0; mf < 4; ++mf) {                                  \
            af[mf][0] = *(const shortx8*)((Ab) + aRd + 8192 + mf * 1024 + ru0); \
            af[mf][1] = *(const shortx8*)((Ab) + aRd + 8192 + mf * 1024 + ru1); \
        } }
#define RD_BLO(Bb) {                                                      \
_Pragma("unroll")                                                         \
        for (int nf = 0; nf < 2; ++nf) {                                  \
            blo[nf][0] = *(const shortx8*)((Bb) + bRd + nf * 1024 + ru0); \
            blo[nf][1] = *(const shortx8*)((Bb) + bRd + nf * 1024 + ru1); \
        } }
#define MFMA_LO { __builtin_amdgcn_s_setprio(1);                          \
_Pragma("unroll")                                                         \
        for (int mf = 0; mf < 4; ++mf)                                    \
_Pragma("unroll")                                                         \
            for (int nf = 0; nf < 2; ++nf) {                              \
                MF(af[mf][0], blo[nf][0], acc[mf][nf]);                   \
                MF(af[mf][1], blo[nf][1], acc[mf][nf]);                   \
            }                                                             \
        __builtin_amdgcn_s_setprio(0); }
#define MFMA_HI { __builtin_amdgcn_s_setprio(1);                          \
_Pragma("unroll")                                                         \
        for (int mf = 0; mf < 4; ++mf)                                    \
_Pragma("unroll")                                                         \
            for (int nf = 0; nf < 2; ++nf) {                              \
                MF(af[mf][0], blo[nf][0], acc[4 + mf][nf]);               \
                MF(af[mf][1], blo[nf][1], acc[4 + mf][nf]);               \
            }                                                             \
        __builtin_amdgcn_s_setprio(0); }

    const int NT = K >> 6;

    if constexpr (BN == 256) {
        // prologue: stage tile 0 in consumption order
        S_A0(0, 0) S_B0(0, 0) S_B1(0, 0) S_A1(0, 0)
        for (int t = 0; t < NT - 1; ++t) {
            const int rb = t & 1, wbuf = rb ^ 1, kc = (t + 1) * 64;
            const short* Ab = Ls + rb * BUFSZ;
            const short* Bb = Ab + 16384;
            // ---- P1: q0 = A-lo x B-lo ----
            WAITV(4); __builtin_amdgcn_s_barrier(); FENCE;
            RD_ALO(Ab) RD_BLO(Bb)
            S_A0(wbuf, kc)
            MFMA_LO
            // ---- P2: q1 = A-lo x B-hi ----
            WAITV(4); __builtin_amdgcn_s_barrier(); FENCE;
#pragma unroll
            for (int nf = 0; nf < 2; ++nf) {
                bhi[nf][0] = *(const shortx8*)(Bb + bRd + 8192 + nf * 1024 + ru0);
                bhi[nf][1] = *(const shortx8*)(Bb + bRd + 8192 + nf * 1024 + ru1);
            }
            S_B0(wbuf, kc)
            __builtin_amdgcn_s_setprio(1);
#pragma unroll
            for (int mf = 0; mf < 4; ++mf)
#pragma unroll
                for (int nf = 0; nf < 2; ++nf) {
                    MF(af[mf][0], bhi[nf][0], acc[mf][2 + nf]);
                    MF(af[mf][1], bhi[nf][1], acc[mf][2 + nf]);
                }
            __builtin_amdgcn_s_setprio(0);
            // ---- P3: q2 = A-hi x B-lo ----
            WAITV(4); __builtin_amdgcn_s_barrier(); FENCE;
            RD_AHI(Ab)
            S_B1(wbuf, kc)
            MFMA_HI
            // ---- P4: q3 = A-hi x B-hi ----
            S_A1(wbuf, kc)
            __builtin_amdgcn_s_setprio(1);
#pragma unroll
            for (int mf = 0; mf < 4; ++mf)
#pragma unroll
                for (int nf = 0; nf < 2; ++nf) {
                    MF(af[mf][0], bhi[nf][0], acc[4 + mf][2 + nf]);
                    MF(af[mf][1], bhi[nf][1], acc[4 + mf][2 + nf]);
                }
            __builtin_amdgcn_s_setprio(0);
        }
        // ---- tail tile ----
        {
            const int rb = (NT - 1) & 1;
            const short* Ab = Ls + rb * BUFSZ;
            const short* Bb = Ab + 16384;
            WAITV(4); __builtin_amdgcn_s_barrier(); FENCE;
            RD_ALO(Ab) RD_BLO(Bb)
            MFMA_LO
            WAITV(2); __builtin_amdgcn_s_barrier(); FENCE;
#pragma unroll
            for (int nf = 0; nf < 2; ++nf) {
                bhi[nf][0] = *(const shortx8*)(Bb + bRd + 8192 + nf * 1024 + ru0);
                bhi[nf][1] = *(const shortx8*)(Bb + bRd + 8192 + nf * 1024 + ru1);
            }
            __builtin_amdgcn_s_setprio(1);
#pragma unroll
            for (int mf = 0; mf < 4; ++mf)
#pragma unroll
                for (int nf = 0; nf < 2; ++nf) {
                    MF(af[mf][0], bhi[nf][0], acc[mf][2 + nf]);
                    MF(af[mf][1], bhi[nf][1], acc[mf][2 + nf]);
                }
            __builtin_amdgcn_s_setprio(0);
            WAITV(0); __builtin_amdgcn_s_barrier(); FENCE;
            RD_AHI(Ab)
            __builtin_amdgcn_s_setprio(1);
#pragma unroll
            for (int mf = 0; mf < 4; ++mf)
#pragma unroll
                for (int nf = 0; nf < 2; ++nf) {
                    MF(af[mf][0], blo[nf][0], acc[4 + mf][nf]);
                    MF(af[mf][1], blo[nf][1], acc[4 + mf][nf]);
                    MF(af[mf][0], bhi[nf][0], acc[4 + mf][2 + nf]);
                    MF(af[mf][1], bhi[nf][1], acc[4 + mf][2 + nf]);
                }
            __builtin_amdgcn_s_setprio(0);
        }
    } else {
        // -------- BN == 128: 2-phase, 3-buffer, prefetch 2 K-tiles ahead --------
        S_A0(0, 0) S_B0(0, 0) S_A1(0, 0)
        S_A0(1, 64) S_B0(1, 64) S_A1(1, 64)
        for (int t = 0; t < NT - 2; ++t) {
            const int rb = t % 3, pb = (t + 2) % 3, kc = (t + 2) * 64;
            const short* Ab = Ls + rb * BUFSZ;
            const short* Bb = Ab + 16384;
            // ---- P1: A-lo x B ----
            WAITV(8); __builtin_amdgcn_s_barrier(); FENCE;
            RD_ALO(Ab) RD_BLO(Bb)
            S_A0(pb, kc)
            MFMA_LO
            // ---- P2: A-hi x B ----
            WAITV(8); __builtin_amdgcn_s_barrier(); FENCE;
            RD_AHI(Ab)
            S_B0(pb, kc) S_A1(pb, kc)
            MFMA_HI
        }
        // ---- tile NT-2 (no staging; drains 8 -> 6) ----
        {
            const int rb = (NT - 2) % 3;
            const short* Ab = Ls + rb * BUFSZ;
            const short* Bb = Ab + 16384;
            WAITV(8); __builtin_amdgcn_s_barrier(); FENCE;
            RD_ALO(Ab) RD_BLO(Bb)
            MFMA_LO
            WAITV(6); __builtin_amdgcn_s_barrier(); FENCE;
            RD_AHI(Ab)
            MFMA_HI
        }
        // ---- tile NT-1 (drains 2 -> 0) ----
        {
            const int rb = (NT - 1) % 3;
            const short* Ab = Ls + rb * BUFSZ;
            const short* Bb = Ab + 16384;
            WAITV(2); __builtin_amdgcn_s_barrier(); FENCE;
            RD_ALO(Ab) RD_BLO(Bb)
            MFMA_LO
            WAITV(0); __builtin_amdgcn_s_barrier(); FENCE;
            RD_AHI(Ab)
            MFMA_HI
        }
    }

    // ---- epilogue ----
#pragma unroll
    for (int mf = 0; mf < 8; ++mf) {
        const int grow0 = by * 256 + (mf >> 2) * 128 + wm * 64 + (mf & 3) * 16 + quad * 4;
#pragma unroll
        for (int nf = 0; nf < NF; ++nf) {
            int gcol;
            if constexpr (BN == 256)
                gcol = bx * 256 + (nf >> 1) * 128 + wn * 32 + (nf & 1) * 16 + l16;
            else
                gcol = bx * 128 + wn * 32 + nf * 16 + l16;
            const floatx4 a = acc[mf][nf];
            if constexpr (EPI == 5) {
                const int slice = gcol >> 10, c = gcol & 1023;
                const int hh = c >> 6, d = c & 63;
                const int b = grow0 >> 11, s0 = grow0 & 2047;
                if (slice == 2) {
                    short* vt = outb + ((size_t)16 << 20);
                    shortx4 pkv;
#pragma unroll
                    for (int r = 0; r < 4; ++r) pkv[r] = f2bs(a[r]);
                    *(shortx4*)(vt + ((size_t)((b * 16 + hh) * 64 + d)) * 2048 + s0) = pkv;
                } else {
                    short* dst = slice ? (outb + ((size_t)8 << 20)) : outb;
                    // Q scale folds 1/sqrt(dk) AND log2(e) so softmax uses raw exp2
                    float sc = slice ? 1.f : 0.125f * 1.4426950408889634f;
#pragma unroll
                    for (int r = 0; r < 4; ++r)
                        dst[(((size_t)(b * 16 + hh)) * 2048 + (s0 + r)) * 64 + d] =
                            f2bs(a[r] * sc);
                }
            } else if constexpr (EPI == 1) {
                const float bv = bias[gcol];
#pragma unroll
                for (int r = 0; r < 4; ++r) {
                    float v = fmaxf(a[r] + bv, 0.f);
                    outb[(size_t)(grow0 + r) * N + gcol] = f2bs(v);
                }
            } else if constexpr (EPI == 2) {
#pragma unroll
                for (int r = 0; r < 4; ++r)
                    outf[(size_t)(grow0 + r) * N + gcol] =
                        a[r] + resf[(size_t)(grow0 + r) * N + gcol];
            } else if constexpr (EPI == 3) {
                const float bv = bias[gcol];
#pragma unroll
                for (int r = 0; r < 4; ++r)
                    outf[(size_t)(grow0 + r) * N + gcol] =
                        a[r] + bv + resf[(size_t)(grow0 + r) * N + gcol];
            }
        }
    }
#undef S_A0
#undef S_A1
#undef S_B0
#undef S_B1
#undef MF
#undef RD_ALO
#undef RD_AHI
#undef RD_BLO
#undef MFMA_LO
#undef MFMA_HI
}

// ---------------- LayerNorm over D=1024, one block per row ----------------
__global__ __launch_bounds__(256) void ln_kernel(
    const float* __restrict__ in, float* __restrict__ outf, short* __restrict__ outb,
    const float* __restrict__ g, const float* __restrict__ be, int writeB)
{
    __shared__ float red[8];
    const int row = blockIdx.x, tid = threadIdx.x;
    const float* p = in + (size_t)row * 1024;
    floatx4 v = *(const floatx4*)(p + tid * 4);
    float s = v[0] + v[1] + v[2] + v[3];
    float q = v[0] * v[0] + v[1] * v[1] + v[2] * v[2] + v[3] * v[3];
#pragma unroll
    for (int off = 32; off; off >>= 1) {
        s += __shfl_xor(s, off);
        q += __shfl_xor(q, off);
    }
    int w = tid >> 6, lane = tid & 63;
    if (lane == 0) { red[w] = s; red[4 + w] = q; }
    __syncthreads();
    s = red[0] + red[1] + red[2] + red[3];
    q = red[4] + red[5] + red[6] + red[7];
    float mean = s * (1.f / 1024.f);
    float var = q * (1.f / 1024.f) - mean * mean;
    float rs = rsqrtf(var + 1e-5f);
    floatx4 gv = *(const floatx4*)(g + tid * 4);
    floatx4 bv = *(const floatx4*)(be + tid * 4);
    floatx4 o4;
#pragma unroll
    for (int i = 0; i < 4; ++i) o4[i] = (v[i] - mean) * rs * gv[i] + bv[i];
    *(floatx4*)(outf + (size_t)row * 1024 + tid * 4) = o4;
    if (writeB) {
        shortx4 ob;
#pragma unroll
        for (int i = 0; i < 4; ++i) ob[i] = f2bs(o4[i]);
        *(shortx4*)(outb + (size_t)row * 1024 + tid * 4) = ob;
    }
}

// ---------------- Flash attention, 32x32x16, dbuf KVBLK=64, 4 blocks/CU ------------
// Q,K: [B*H][2048][64] bf16 (Q pre-scaled by log2e/8). Vt: [B*H][64][2048] bf16.
// ctx out: [8192][1024] bf16. BQ=128 (32 q-rows/wave). grid=(64,16): bx=bh so
// blockId%8 = bh%8 -> all 16 q-tiles of a head pinned to one XCD (K/V L2-resident;
// r7-validated FETCH 139->27MB). 1024 blocks = 4 blocks/CU.
// K tile [64][64], Vt tile [64][64]; both unit_phys = unit_log ^ (row&7), staged
// via pre-swizzled global source col (gload_lds dest linear). Double-buffered:
// iter kt: WAITV(0) (kt's loads, issued before compute kt-1 -> latency covered);
// s_barrier (also guards WAR on buf being overwritten); issue kt+1 stage; compute.
__global__ __launch_bounds__(256, 4) void attn_kernel(
    const short* __restrict__ Q, const short* __restrict__ K,
    const short* __restrict__ Vt, short* __restrict__ ctx)
{
    __shared__ __align__(16) short Ls[16384];  // 32 KB: 2 x {K[64][64], V[64][64]}
    const int tid = threadIdx.x;
    const int bh = blockIdx.x, q0 = blockIdx.y * 128;
    const int w = tid >> 6, lane = tid & 63, l31 = lane & 31, hl = lane >> 5;
    const size_t sb = (size_t)bh * 2048 * 64;

    shortx8 qf[4];
#pragma unroll
    for (int ks = 0; ks < 4; ++ks)
        qf[ks] = *(const shortx8*)(Q + sb + (size_t)(q0 + w * 32 + l31) * 64 + ks * 16 + hl * 8);

    // staging: sweep j covers rows j*32 + w*8 + (lane>>3); phys unit = lane&7;
    // source logical unit = (lane&7) ^ (row&7), row&7 = lane>>3.
    const int srow = w * 8 + (lane >> 3);
    const int sunit = ((lane & 7) ^ (lane >> 3)) * 8;
    const short* kSrc = K + sb + (size_t)srow * 64 + sunit;        // + kv0*64 + j*2048
    const short* vSrc = Vt + sb + (size_t)srow * 2048 + sunit;     // + kv0 + j*65536
    const int sdst = w * 512;                                      // + buf*8192 + j*2048

    // read-side swizzle component
    const int kx = l31 & 7;

    floatx16 o[2] = {};
    floatx2 rsA = {0.f, 0.f}, rsB = {0.f, 0.f};
    const floatx16 z = {};

#define STAGE(buf, kv0) { \
    short* kb = Ls + (buf) * 8192 + sdst; \
    gload16(kSrc + (size_t)(kv0) * 64, kb); \
    gload16(kSrc + (size_t)(kv0) * 64 + 2048, kb + 2048); \
    gload16(vSrc + (kv0), kb + 4096); \
    gload16(vSrc + (kv0) + 65536, kb + 6144); \
    FENCE; }

#define LD_AK(B, mt, ks) (*(const shortx8*)((B) + ((mt) * 32 + l31) * 64 + ((((ks) * 2 + hl) ^ kx)) * 8))
#define LD_AV(B, mtd, mt, ksl) (*(const shortx8*)((B) + 4096 + ((mtd) * 32 + l31) * 64 + ((((mt) * 4 + (ksl) * 2 + hl) ^ kx)) * 8))
#define MFA(a, b, c) __builtin_amdgcn_mfma_f32_32x32x16_bf16(a, b, c, 0, 0, 0)

    STAGE(0, 0)

    for (int kt = 0; kt < 32; ++kt) {
        WAITV(0);                       // tile kt staged (issued 1 compute phase ago)
        __builtin_amdgcn_s_barrier();   // all waves: loads drained + prev reads done
        FENCE;
        if (kt < 31) STAGE((kt + 1) & 1, (kt + 1) * 64)
        const short* B = Ls + (kt & 1) * 8192;

#pragma unroll
        for (int mt = 0; mt < 2; ++mt) {
            floatx16 sc;
            __builtin_amdgcn_s_setprio(1);
            sc = MFA(LD_AK(B, mt, 0), qf[0], z);
            sc = MFA(LD_AK(B, mt, 1), qf[1], sc);
            sc = MFA(LD_AK(B, mt, 2), qf[2], sc);
            sc = MFA(LD_AK(B, mt, 3), qf[3], sc);
            __builtin_amdgcn_s_setprio(0);
            // exp2 (log2e folded into Q), packed pairwise sum (2 accumulators)
            floatx2 ps2[8];
#pragma unroll
            for (int i = 0; i < 8; ++i) {
                ps2[i][0] = fexp2(sc[2 * i]);
                ps2[i][1] = fexp2(sc[2 * i + 1]);
            }
#pragma unroll
            for (int i = 0; i < 8; i += 2) { rsA += ps2[i]; rsB += ps2[i + 1]; }
            unsigned pk[8];
#pragma unroll
            for (int i = 0; i < 8; ++i) {
                union { __hip_bfloat162 h; unsigned u; } cv;
                cv.h = __float22bfloat162_rn(make_float2(ps2[i][0], ps2[i][1]));
                pk[i] = cv.u;
            }
            // half-lane swaps: [pk0..pk3] = B-frag kv 0..15, [pk4..pk7] = kv 16..31
            lane32swap(pk[0], pk[2]);
            lane32swap(pk[1], pk[3]);
            lane32swap(pk[4], pk[6]);
            lane32swap(pk[5], pk[7]);
            __builtin_amdgcn_s_setprio(1);
#pragma unroll
            for (int ksl = 0; ksl < 2; ++ksl) {
                union { unsigned i[4]; shortx8 s8; } fr;
                fr.i[0] = pk[4 * ksl];     fr.i[1] = pk[4 * ksl + 1];
                fr.i[2] = pk[4 * ksl + 2]; fr.i[3] = pk[4 * ksl + 3];
#pragma unroll
                for (int mtd = 0; mtd < 2; ++mtd)
                    o[mtd] = MFA(LD_AV(B, mtd, mt, ksl), fr.s8, o[mtd]);
            }
            __builtin_amdgcn_s_setprio(0);
        }
    }
#undef STAGE
#undef LD_AK
#undef LD_AV
#undef MFA

    float rsum = rsA[0] + rsA[1] + rsB[0] + rsB[1];
    float tot = rsum + __shfl_xor(rsum, 32);
    float inv = 1.f / tot;

    __syncthreads();
    short* O_lds = Ls;   // 128 rows x 72 shorts = 18 KB, fits in 32 KB
#pragma unroll
    for (int mtd = 0; mtd < 2; ++mtd)
#pragma unroll
        for (int g = 0; g < 4; ++g) {
            shortx4 p4;
#pragma unroll
            for (int r = 0; r < 4; ++r) p4[r] = f2bs(o[mtd][4 * g + r] * inv);
            *(shortx4*)(O_lds + (w * 32 + l31) * 72 + mtd * 32 + g * 8 + hl * 4) = p4;
        }
    __syncthreads();
    const int b = bh >> 4, head = bh & 15;
#pragma unroll
    for (int it = 0; it < 4; ++it) {
        int idx = it * 256 + tid;
        int q = idx >> 3, ch = idx & 7;
        shortx8 v = *(const shortx8*)(O_lds + q * 72 + ch * 8);
        *(shortx8*)(ctx + ((size_t)(b * 2048 + q0 + q)) * 1024 + head * 64 + ch * 8) = v;
    }
}

// ---------------- launch ----------------
extern "C" void kernel_launch(void* const* d_in, const int* in_sizes, int n_in,
                              void* d_out, int out_size, void* d_ws, size_t ws_size,
                              hipStream_t stream) {
    const float* x   = (const float*)d_in[0];
    const float* wq  = (const float*)d_in[1];
    const float* wk  = (const float*)d_in[2];
    const float* wv  = (const float*)d_in[3];
    const float* wo  = (const float*)d_in[4];
    const float* w1  = (const float*)d_in[5];
    const float* b1  = (const float*)d_in[6];
    const float* w2  = (const float*)d_in[7];
    const float* b2  = (const float*)d_in[8];
    const float* g1p = (const float*)d_in[9];
    const float* be1 = (const float*)d_in[10];
    const float* g2p = (const float*)d_in[11];
    const float* be2 = (const float*)d_in[12];
    float* out = (float*)d_out;

    char* ws = (char*)d_ws;
    const size_t MB = 1ull << 20;
    short* wqt  = (short*)(ws + 0 * MB);
    short* wkt  = (short*)(ws + 2 * MB);
    short* wvt  = (short*)(ws + 4 * MB);
    short* wot  = (short*)(ws + 6 * MB);
    short* w1t  = (short*)(ws + 8 * MB);
    short* w2t  = (short*)(ws + 16 * MB);
    short* xb   = (short*)(ws + 24 * MB);
    short* Qb   = (short*)(ws + 40 * MB);   // K at +16MB, Vt at +32MB (EPI5 offsets)
    short* Kb   = (short*)(ws + 56 * MB);
    short* Vtg  = (short*)(ws + 72 * MB);
    short* ctxb = (short*)(ws + 88 * MB);
    float* tf   = (float*)(ws + 104 * MB);
    short* hb   = (short*)(ws + 136 * MB);
    short* f1b  = (short*)(ws + 40 * MB);   // reuses Qb..ctxb (dead by then)

    prep_kernel<<<5120, 256, 0, stream>>>(wq, wk, wv, wo, w1, w2, x,
                                          wqt, wkt, wvt, wot, w1t, w2t, xb);

    gemm256<5, 128><<<dim3(24, 32), 512, 0, stream>>>(xb, wqt, 1024, 3072, Qb, nullptr, nullptr, nullptr);
    attn_kernel<<<dim3(64, 16), 256, 0, stream>>>(Qb, Kb, Vtg, ctxb);
    gemm256<2, 128><<<dim3(8, 32), 512, 0, stream>>>(ctxb, wot, 1024, 1024, nullptr, tf, nullptr, x);
    ln_kernel<<<8192, 256, 0, stream>>>(tf, tf, hb, g1p, be1, 1);
    gemm256<1, 128><<<dim3(32, 32), 512, 0, stream>>>(hb, w1t, 1024, 4096, f1b, nullptr, b1, nullptr);
    gemm256<3, 128><<<dim3(8, 32), 512, 0, stream>>>(f1b, w2t, 4096, 1024, nullptr, out, b2, tf);
    ln_kernel<<<8192, 256, 0, stream>>>(out, out, nullptr, g2p, be2, 0);
}

// Round 11
// 351.756 us; speedup vs baseline: 1.9671x; 1.0458x over previous
//
#include <hip/hip_runtime.h>
#include <hip/hip_bf16.h>

// MyTransformerEncoderBlock: B=4, S=2048, D=1024, H=16, dk=64, D_FF=4096
// Round 17: best-of recombination.
//  - attn: round-16 config kept (32q/wave, dbuf KVBLK=64, grid (64,16) XCD-pinned,
//    88.3us, VGPR 52, FETCH 30MB).
//  - FFN1: reverted to BN=256 2-buf 4-phase grid (16,32) (BN=128 at N=4096 halves
//    B-panel reuse -> ~15us regression measured in round 16).
//  - QKV/WO/FFN2 on BN=128 3-buf; XCD remap everywhere; LN/prep unchanged.

typedef float  floatx2  __attribute__((ext_vector_type(2)));
typedef float  floatx4  __attribute__((ext_vector_type(4)));
typedef float  floatx16 __attribute__((ext_vector_type(16)));
typedef short  shortx8  __attribute__((ext_vector_type(8)));
typedef short  shortx4  __attribute__((ext_vector_type(4)));
typedef int    intx4    __attribute__((ext_vector_type(4)));
typedef unsigned uintx2 __attribute__((ext_vector_type(2)));

__device__ __forceinline__ short f2bs(float f) {  // fp32 -> bf16 bits (RTNE)
    union { float f; unsigned u; } a; a.f = f;
    unsigned r = a.u + 0x7fffu + ((a.u >> 16) & 1u);
    return (short)(r >> 16);
}

__device__ __forceinline__ float fexp2(float x) {
#if __has_builtin(__builtin_amdgcn_exp2f)
    return __builtin_amdgcn_exp2f(x);
#else
    return __expf(0.6931471805599453f * x);
#endif
}

// swap: a's hi-32-lanes <-> b's lo-32-lanes (v_permlane32_swap_b32)
__device__ __forceinline__ void lane32swap(unsigned& a, unsigned& b) {
#if __has_builtin(__builtin_amdgcn_permlane32_swap)
    uintx2 r = __builtin_amdgcn_permlane32_swap(a, b, false, false);
    a = r[0]; b = r[1];
#else
    int hl = (threadIdx.x & 63) >> 5;
    unsigned ta = (unsigned)__shfl_xor((int)a, 32);
    unsigned tb = (unsigned)__shfl_xor((int)b, 32);
    unsigned na = hl ? tb : a;
    unsigned nb = hl ? b : ta;
    a = na; b = nb;
#endif
}

__device__ __forceinline__ void gload16(const short* g, short* l) {
    __builtin_amdgcn_global_load_lds(
        (const __attribute__((address_space(1))) void*)g,
        (__attribute__((address_space(3))) void*)l,
        16, 0, 0);
}

#define WAITV(n) asm volatile("s_waitcnt vmcnt(" #n ")" ::: "memory")
#define FENCE    asm volatile("" ::: "memory")

// ---------------- fused prep: 6 weight transposes + x cast, one launch ----------------
__device__ __forceinline__ void trans_tile(const float* __restrict__ in,
                                           short* __restrict__ out,
                                           int N, int K, int k0, int n0,
                                           short (*t)[68]) {
    const int tid = threadIdx.x;
    const int r = tid >> 4, c4 = (tid & 15) * 4;
#pragma unroll
    for (int i = 0; i < 4; ++i) {
        int k = r + i * 16;
        floatx4 v = *(const floatx4*)(in + (size_t)(k0 + k) * N + n0 + c4);
        shortx4 s;
#pragma unroll
        for (int j = 0; j < 4; ++j) s[j] = f2bs(v[j]);
        *(shortx4*)(&t[k][c4]) = s;
    }
    __syncthreads();
#pragma unroll
    for (int i = 0; i < 4; ++i) {
        int n = r + i * 16;
        shortx4 s;
#pragma unroll
        for (int j = 0; j < 4; ++j) s[j] = t[c4 + j][n];
        *(shortx4*)(out + (size_t)(n0 + n) * K + k0 + c4) = s;
    }
}

__global__ __launch_bounds__(256) void prep_kernel(
    const float* __restrict__ wq, const float* __restrict__ wk,
    const float* __restrict__ wv, const float* __restrict__ wo,
    const float* __restrict__ w1, const float* __restrict__ w2,
    const float* __restrict__ x,
    short* wqt, short* wkt, short* wvt, short* wot,
    short* w1t, short* w2t, short* xb)
{
    __shared__ __align__(16) short t[64][68];
    const int bid = blockIdx.x;
    if (bid < 1024) {
        const int widx = bid >> 8, local = bid & 255;
        const float* in = widx == 0 ? wq : widx == 1 ? wk : widx == 2 ? wv : wo;
        short* out = widx == 0 ? wqt : widx == 1 ? wkt : widx == 2 ? wvt : wot;
        trans_tile(in, out, 1024, 1024, (local & 15) * 64, (local >> 4) * 64, t);
    } else if (bid < 2048) {
        const int local = bid - 1024;
        trans_tile(w1, w1t, 4096, 1024, (local & 15) * 64, (local >> 4) * 64, t);
    } else if (bid < 3072) {
        const int local = bid - 2048;
        trans_tile(w2, w2t, 1024, 4096, (local & 63) * 64, (local >> 6) * 64, t);
    } else {
        const int local = bid - 3072;
#pragma unroll
        for (int j = 0; j < 4; ++j) {
            int i = local * 1024 + j * 256 + threadIdx.x;
            floatx4 v = *(const floatx4*)(x + (size_t)i * 4);
            shortx4 o;
            o[0] = f2bs(v[0]); o[1] = f2bs(v[1]); o[2] = f2bs(v[2]); o[3] = f2bs(v[3]);
            *(shortx4*)(xb + (size_t)i * 4) = o;
        }
    }
}

// ---------------- GEMM: 256xBN tile, BK=64, 8 waves, counted-vmcnt pipeline ----------
// C[M,N] = A[M,K](bf16) * Bt[N,K]^T(bf16).
// BN=256: LDS 128KB (2 buf), 4 phases/K-tile, stage order A0,B0,B1,A1, WAITV(4).
// BN=128: LDS 144KB (3 buf), 2 phases/K-tile, prefetch 2 tiles ahead, WAITV(8).
// XCD remap: h=(bx+by*gridX); xcd=h&7 owns 4 consecutive by-panels -> A-panel L2
// reuse within an XCD (requires gridY==32, total%8==0; bijective).
// XOR swizzle: 16B-unit u_phys = u_log ^ ((row>>1)&7); applied on global SOURCE col
// (global_load_lds dest stays linear) and on ds_read addresses -> conflict-free reads.
// EPI 1: +bias, relu, bf16 (FFN1)   EPI 2: +resf fp32 (WO)
// EPI 3: +bias+resf fp32 (FFN2)     EPI 5: fused QKV scatter
template<int EPI, int BN>
__global__ __launch_bounds__(512, 2) void gemm256(
    const short* __restrict__ A, const short* __restrict__ Bt, const int K, const int N,
    short* __restrict__ outb, float* __restrict__ outf,
    const float* __restrict__ bias, const float* __restrict__ resf)
{
    constexpr int BUFSZ = 16384 + BN * 64;   // shorts per buffer (A 256x64 + B BNx64)
    constexpr int NF = BN / 64;              // acc N-frags per wave
    constexpr int NBUF = (BN == 128) ? 3 : 2;
    __shared__ __align__(16) short Ls[NBUF * BUFSZ];
    const int tid = threadIdx.x;
    const int w = tid >> 6, lane = tid & 63;
    const int quad = lane >> 4, l16 = lane & 15;
    const int wm = w >> 2, wn = w & 3;          // 2 x 4 wave grid
    // XCD-aware remap: xcd = h&7 gets by in [xcd*4, xcd*4+4), bx sweeps all.
    const int hsw = blockIdx.x + blockIdx.y * gridDim.x;
    const int vv = hsw >> 3;
    const int by = (hsw & 7) * 4 + (vv & 3);
    const int bx = vv >> 2;

    // staging source (per-lane, col pre-swizzled so linear LDS dest = swizzled layout)
    const int srow = w * 16 + (lane >> 3);
    const int uc0 = ((lane & 7) ^ ((lane >> 4) & 7)) * 8;          // gi=0
    const int uc1 = ((lane & 7) ^ (((lane >> 4) + 4) & 7)) * 8;    // gi=1
    const short* aS0 = A  + (size_t)(by * 256 + srow) * K + uc0;
    const short* aS1 = A  + (size_t)(by * 256 + srow + 8) * K + uc1;
    const short* bS0 = Bt + (size_t)(bx * BN + srow) * K + uc0;
    const short* bS1 = Bt + (size_t)(bx * BN + srow + 8) * K + uc1;
    const size_t hK = (size_t)128 * K;          // +128 rows
    const int wsl = w * 1024;                   // wave's staging slice (shorts)

    // ds_read offsets (shorts). rswz constant per thread: row bases are mult of 16.
    const int rswz = (l16 >> 1) & 7;
    const int ru0 = (quad ^ rswz) * 8;          // ks=0 swizzled unit
    const int ru1 = ((4 + quad) ^ rswz) * 8;    // ks=1 swizzled unit
    const int aRd = (wm * 64 + l16) * 64;
    const int bRd = (wn * 32 + l16) * 64;

    floatx4 acc[8][NF] = {};
    shortx8 af[4][2], blo[2][2], bhi[2][2];

#define S_A0(buf, kc) { short* p = Ls + (buf) * BUFSZ + wsl;         gload16(aS0 + (kc), p);      gload16(aS1 + (kc), p + 512);      FENCE; }
#define S_A1(buf, kc) { short* p = Ls + (buf) * BUFSZ + 8192 + wsl;  gload16(aS0 + hK + (kc), p); gload16(aS1 + hK + (kc), p + 512); FENCE; }
#define S_B0(buf, kc) { short* p = Ls + (buf) * BUFSZ + 16384 + wsl; gload16(bS0 + (kc), p);      gload16(bS1 + (kc), p + 512);      FENCE; }
#define S_B1(buf, kc) { short* p = Ls + (buf) * BUFSZ + 24576 + wsl; gload16(bS0 + hK + (kc), p); gload16(bS1 + hK + (kc), p + 512); FENCE; }
#define MF(a, b, c) c = __builtin_amdgcn_mfma_f32_16x16x32_bf16(a, b, c, 0, 0, 0)

#define RD_ALO(Ab) {                                                      \
_Pragma("unroll")                                                         \
        for (int mf = 0; mf < 4; ++mf) {                                  \
            af[mf][0] = *(const shortx8*)((Ab) + aRd + mf * 1024 + ru0);  \
            af[mf][1] = *(const shortx8*)((Ab) + aRd + mf * 1024 + ru1);  \
        } }
#define RD_AHI(Ab) {                                                      \
_Pragma("unroll")                                                         \
        for (int mf = 0; mf < 4; ++mf) {                                  \
            af[mf][0] = *(const shortx8*)((Ab) + aRd + 8192 + mf * 1024 + ru0); \
            af[mf][1] = *(const shortx8*)((Ab) + aRd + 8192 + mf * 1024 + ru1); \
        } }
#define RD_BLO(Bb) {                                                      \
_Pragma("unroll")                                                         \
        for (int nf = 0; nf < 2; ++nf) {                                  \
            blo[nf][0] = *(const shortx8*)((Bb) + bRd + nf * 1024 + ru0); \
            blo[nf][1] = *(const shortx8*)((Bb) + bRd + nf * 1024 + ru1); \
        } }
#define MFMA_LO { __builtin_amdgcn_s_setprio(1);                          \
_Pragma("unroll")                                                         \
        for (int mf = 0; mf < 4; ++mf)                                    \
_Pragma("unroll")                                                         \
            for (int nf = 0; nf < 2; ++nf) {                              \
                MF(af[mf][0], blo[nf][0], acc[mf][nf]);                   \
                MF(af[mf][1], blo[nf][1], acc[mf][nf]);                   \
            }                                                             \
        __builtin_amdgcn_s_setprio(0); }
#define MFMA_HI { __builtin_amdgcn_s_setprio(1);                          \
_Pragma("unroll")                                                         \
        for (int mf = 0; mf < 4; ++mf)                                    \
_Pragma("unroll")                                                         \
            for (int nf = 0; nf < 2; ++nf) {                              \
                MF(af[mf][0], blo[nf][0], acc[4 + mf][nf]);               \
                MF(af[mf][1], blo[nf][1], acc[4 + mf][nf]);               \
            }                                                             \
        __builtin_amdgcn_s_setprio(0); }

    const int NT = K >> 6;

    if constexpr (BN == 256) {
        // prologue: stage tile 0 in consumption order
        S_A0(0, 0) S_B0(0, 0) S_B1(0, 0) S_A1(0, 0)
        for (int t = 0; t < NT - 1; ++t) {
            const int rb = t & 1, wbuf = rb ^ 1, kc = (t + 1) * 64;
            const short* Ab = Ls + rb * BUFSZ;
            const short* Bb = Ab + 16384;
            // ---- P1: q0 = A-lo x B-lo ----
            WAITV(4); __builtin_amdgcn_s_barrier(); FENCE;
            RD_ALO(Ab) RD_BLO(Bb)
            S_A0(wbuf, kc)
            MFMA_LO
            // ---- P2: q1 = A-lo x B-hi ----
            WAITV(4); __builtin_amdgcn_s_barrier(); FENCE;
#pragma unroll
            for (int nf = 0; nf < 2; ++nf) {
                bhi[nf][0] = *(const shortx8*)(Bb + bRd + 8192 + nf * 1024 + ru0);
                bhi[nf][1] = *(const shortx8*)(Bb + bRd + 8192 + nf * 1024 + ru1);
            }
            S_B0(wbuf, kc)
            __builtin_amdgcn_s_setprio(1);
#pragma unroll
            for (int mf = 0; mf < 4; ++mf)
#pragma unroll
                for (int nf = 0; nf < 2; ++nf) {
                    MF(af[mf][0], bhi[nf][0], acc[mf][2 + nf]);
                    MF(af[mf][1], bhi[nf][1], acc[mf][2 + nf]);
                }
            __builtin_amdgcn_s_setprio(0);
            // ---- P3: q2 = A-hi x B-lo ----
            WAITV(4); __builtin_amdgcn_s_barrier(); FENCE;
            RD_AHI(Ab)
            S_B1(wbuf, kc)
            MFMA_HI
            // ---- P4: q3 = A-hi x B-hi ----
            S_A1(wbuf, kc)
            __builtin_amdgcn_s_setprio(1);
#pragma unroll
            for (int mf = 0; mf < 4; ++mf)
#pragma unroll
                for (int nf = 0; nf < 2; ++nf) {
                    MF(af[mf][0], bhi[nf][0], acc[4 + mf][2 + nf]);
                    MF(af[mf][1], bhi[nf][1], acc[4 + mf][2 + nf]);
                }
            __builtin_amdgcn_s_setprio(0);
        }
        // ---- tail tile ----
        {
            const int rb = (NT - 1) & 1;
            const short* Ab = Ls + rb * BUFSZ;
            const short* Bb = Ab + 16384;
            WAITV(4); __builtin_amdgcn_s_barrier(); FENCE;
            RD_ALO(Ab) RD_BLO(Bb)
            MFMA_LO
            WAITV(2); __builtin_amdgcn_s_barrier(); FENCE;
#pragma unroll
            for (int nf = 0; nf < 2; ++nf) {
                bhi[nf][0] = *(const shortx8*)(Bb + bRd + 8192 + nf * 1024 + ru0);
                bhi[nf][1] = *(const shortx8*)(Bb + bRd + 8192 + nf * 1024 + ru1);
            }
            __builtin_amdgcn_s_setprio(1);
#pragma unroll
            for (int mf = 0; mf < 4; ++mf)
#pragma unroll
                for (int nf = 0; nf < 2; ++nf) {
                    MF(af[mf][0], bhi[nf][0], acc[mf][2 + nf]);
                    MF(af[mf][1], bhi[nf][1], acc[mf][2 + nf]);
                }
            __builtin_amdgcn_s_setprio(0);
            WAITV(0); __builtin_amdgcn_s_barrier(); FENCE;
            RD_AHI(Ab)
            __builtin_amdgcn_s_setprio(1);
#pragma unroll
            for (int mf = 0; mf < 4; ++mf)
#pragma unroll
                for (int nf = 0; nf < 2; ++nf) {
                    MF(af[mf][0], blo[nf][0], acc[4 + mf][nf]);
                    MF(af[mf][1], blo[nf][1], acc[4 + mf][nf]);
                    MF(af[mf][0], bhi[nf][0], acc[4 + mf][2 + nf]);
                    MF(af[mf][1], bhi[nf][1], acc[4 + mf][2 + nf]);
                }
            __builtin_amdgcn_s_setprio(0);
        }
    } else {
        // -------- BN == 128: 2-phase, 3-buffer, prefetch 2 K-tiles ahead --------
        S_A0(0, 0) S_B0(0, 0) S_A1(0, 0)
        S_A0(1, 64) S_B0(1, 64) S_A1(1, 64)
        for (int t = 0; t < NT - 2; ++t) {
            const int rb = t % 3, pb = (t + 2) % 3, kc = (t + 2) * 64;
            const short* Ab = Ls + rb * BUFSZ;
            const short* Bb = Ab + 16384;
            // ---- P1: A-lo x B ----
            WAITV(8); __builtin_amdgcn_s_barrier(); FENCE;
            RD_ALO(Ab) RD_BLO(Bb)
            S_A0(pb, kc)
            MFMA_LO
            // ---- P2: A-hi x B ----
            WAITV(8); __builtin_amdgcn_s_barrier(); FENCE;
            RD_AHI(Ab)
            S_B0(pb, kc) S_A1(pb, kc)
            MFMA_HI
        }
        // ---- tile NT-2 (no staging; drains 8 -> 6) ----
        {
            const int rb = (NT - 2) % 3;
            const short* Ab = Ls + rb * BUFSZ;
            const short* Bb = Ab + 16384;
            WAITV(8); __builtin_amdgcn_s_barrier(); FENCE;
            RD_ALO(Ab) RD_BLO(Bb)
            MFMA_LO
            WAITV(6); __builtin_amdgcn_s_barrier(); FENCE;
            RD_AHI(Ab)
            MFMA_HI
        }
        // ---- tile NT-1 (drains 2 -> 0) ----
        {
            const int rb = (NT - 1) % 3;
            const short* Ab = Ls + rb * BUFSZ;
            const short* Bb = Ab + 16384;
            WAITV(2); __builtin_amdgcn_s_barrier(); FENCE;
            RD_ALO(Ab) RD_BLO(Bb)
            MFMA_LO
            WAITV(0); __builtin_amdgcn_s_barrier(); FENCE;
            RD_AHI(Ab)
            MFMA_HI
        }
    }

    // ---- epilogue ----
#pragma unroll
    for (int mf = 0; mf < 8; ++mf) {
        const int grow0 = by * 256 + (mf >> 2) * 128 + wm * 64 + (mf & 3) * 16 + quad * 4;
#pragma unroll
        for (int nf = 0; nf < NF; ++nf) {
            int gcol;
            if constexpr (BN == 256)
                gcol = bx * 256 + (nf >> 1) * 128 + wn * 32 + (nf & 1) * 16 + l16;
            else
                gcol = bx * 128 + wn * 32 + nf * 16 + l16;
            const floatx4 a = acc[mf][nf];
            if constexpr (EPI == 5) {
                const int slice = gcol >> 10, c = gcol & 1023;
                const int hh = c >> 6, d = c & 63;
                const int b = grow0 >> 11, s0 = grow0 & 2047;
                if (slice == 2) {
                    short* vt = outb + ((size_t)16 << 20);
                    shortx4 pkv;
#pragma unroll
                    for (int r = 0; r < 4; ++r) pkv[r] = f2bs(a[r]);
                    *(shortx4*)(vt + ((size_t)((b * 16 + hh) * 64 + d)) * 2048 + s0) = pkv;
                } else {
                    short* dst = slice ? (outb + ((size_t)8 << 20)) : outb;
                    // Q scale folds 1/sqrt(dk) AND log2(e) so softmax uses raw exp2
                    float sc = slice ? 1.f : 0.125f * 1.4426950408889634f;
#pragma unroll
                    for (int r = 0; r < 4; ++r)
                        dst[(((size_t)(b * 16 + hh)) * 2048 + (s0 + r)) * 64 + d] =
                            f2bs(a[r] * sc);
                }
            } else if constexpr (EPI == 1) {
                const float bv = bias[gcol];
#pragma unroll
                for (int r = 0; r < 4; ++r) {
                    float v = fmaxf(a[r] + bv, 0.f);
                    outb[(size_t)(grow0 + r) * N + gcol] = f2bs(v);
                }
            } else if constexpr (EPI == 2) {
#pragma unroll
                for (int r = 0; r < 4; ++r)
                    outf[(size_t)(grow0 + r) * N + gcol] =
                        a[r] + resf[(size_t)(grow0 + r) * N + gcol];
            } else if constexpr (EPI == 3) {
                const float bv = bias[gcol];
#pragma unroll
                for (int r = 0; r < 4; ++r)
                    outf[(size_t)(grow0 + r) * N + gcol] =
                        a[r] + bv + resf[(size_t)(grow0 + r) * N + gcol];
            }
        }
    }
#undef S_A0
#undef S_A1
#undef S_B0
#undef S_B1
#undef MF
#undef RD_ALO
#undef RD_AHI
#undef RD_BLO
#undef MFMA_LO
#undef MFMA_HI
}

// ---------------- LayerNorm over D=1024, one block per row ----------------
__global__ __launch_bounds__(256) void ln_kernel(
    const float* __restrict__ in, float* __restrict__ outf, short* __restrict__ outb,
    const float* __restrict__ g, const float* __restrict__ be, int writeB)
{
    __shared__ float red[8];
    const int row = blockIdx.x, tid = threadIdx.x;
    const float* p = in + (size_t)row * 1024;
    floatx4 v = *(const floatx4*)(p + tid * 4);
    float s = v[0] + v[1] + v[2] + v[3];
    float q = v[0] * v[0] + v[1] * v[1] + v[2] * v[2] + v[3] * v[3];
#pragma unroll
    for (int off = 32; off; off >>= 1) {
        s += __shfl_xor(s, off);
        q += __shfl_xor(q, off);
    }
    int w = tid >> 6, lane = tid & 63;
    if (lane == 0) { red[w] = s; red[4 + w] = q; }
    __syncthreads();
    s = red[0] + red[1] + red[2] + red[3];
    q = red[4] + red[5] + red[6] + red[7];
    float mean = s * (1.f / 1024.f);
    float var = q * (1.f / 1024.f) - mean * mean;
    float rs = rsqrtf(var + 1e-5f);
    floatx4 gv = *(const floatx4*)(g + tid * 4);
    floatx4 bv = *(const floatx4*)(be + tid * 4);
    floatx4 o4;
#pragma unroll
    for (int i = 0; i < 4; ++i) o4[i] = (v[i] - mean) * rs * gv[i] + bv[i];
    *(floatx4*)(outf + (size_t)row * 1024 + tid * 4) = o4;
    if (writeB) {
        shortx4 ob;
#pragma unroll
        for (int i = 0; i < 4; ++i) ob[i] = f2bs(o4[i]);
        *(shortx4*)(outb + (size_t)row * 1024 + tid * 4) = ob;
    }
}

// ---------------- Flash attention, 32x32x16, dbuf KVBLK=64, 4 blocks/CU ------------
// Q,K: [B*H][2048][64] bf16 (Q pre-scaled by log2e/8). Vt: [B*H][64][2048] bf16.
// ctx out: [8192][1024] bf16. BQ=128 (32 q-rows/wave). grid=(64,16): bx=bh so
// blockId%8 = bh%8 -> all 16 q-tiles of a head pinned to one XCD (K/V L2-resident;
// FETCH 139->30MB validated). 1024 blocks = 4 blocks/CU.
// K tile [64][64], Vt tile [64][64]; both unit_phys = unit_log ^ (row&7), staged
// via pre-swizzled global source col (gload_lds dest linear). Double-buffered:
// iter kt: WAITV(0) (kt's loads, issued before compute kt-1 -> latency covered);
// s_barrier (also guards WAR on buf being overwritten); issue kt+1 stage; compute.
__global__ __launch_bounds__(256, 4) void attn_kernel(
    const short* __restrict__ Q, const short* __restrict__ K,
    const short* __restrict__ Vt, short* __restrict__ ctx)
{
    __shared__ __align__(16) short Ls[16384];  // 32 KB: 2 x {K[64][64], V[64][64]}
    const int tid = threadIdx.x;
    const int bh = blockIdx.x, q0 = blockIdx.y * 128;
    const int w = tid >> 6, lane = tid & 63, l31 = lane & 31, hl = lane >> 5;
    const size_t sb = (size_t)bh * 2048 * 64;

    shortx8 qf[4];
#pragma unroll
    for (int ks = 0; ks < 4; ++ks)
        qf[ks] = *(const shortx8*)(Q + sb + (size_t)(q0 + w * 32 + l31) * 64 + ks * 16 + hl * 8);

    // staging: sweep j covers rows j*32 + w*8 + (lane>>3); phys unit = lane&7;
    // source logical unit = (lane&7) ^ (row&7), row&7 = lane>>3.
    const int srow = w * 8 + (lane >> 3);
    const int sunit = ((lane & 7) ^ (lane >> 3)) * 8;
    const short* kSrc = K + sb + (size_t)srow * 64 + sunit;        // + kv0*64 + j*2048
    const short* vSrc = Vt + sb + (size_t)srow * 2048 + sunit;     // + kv0 + j*65536
    const int sdst = w * 512;                                      // + buf*8192 + j*2048

    // read-side swizzle component
    const int kx = l31 & 7;

    floatx16 o[2] = {};
    floatx2 rsA = {0.f, 0.f}, rsB = {0.f, 0.f};
    const floatx16 z = {};

#define STAGE(buf, kv0) { \
    short* kb = Ls + (buf) * 8192 + sdst; \
    gload16(kSrc + (size_t)(kv0) * 64, kb); \
    gload16(kSrc + (size_t)(kv0) * 64 + 2048, kb + 2048); \
    gload16(vSrc + (kv0), kb + 4096); \
    gload16(vSrc + (kv0) + 65536, kb + 6144); \
    FENCE; }

#define LD_AK(B, mt, ks) (*(const shortx8*)((B) + ((mt) * 32 + l31) * 64 + ((((ks) * 2 + hl) ^ kx)) * 8))
#define LD_AV(B, mtd, mt, ksl) (*(const shortx8*)((B) + 4096 + ((mtd) * 32 + l31) * 64 + ((((mt) * 4 + (ksl) * 2 + hl) ^ kx)) * 8))
#define MFA(a, b, c) __builtin_amdgcn_mfma_f32_32x32x16_bf16(a, b, c, 0, 0, 0)

    STAGE(0, 0)

    for (int kt = 0; kt < 32; ++kt) {
        WAITV(0);                       // tile kt staged (issued 1 compute phase ago)
        __builtin_amdgcn_s_barrier();   // all waves: loads drained + prev reads done
        FENCE;
        if (kt < 31) STAGE((kt + 1) & 1, (kt + 1) * 64)
        const short* B = Ls + (kt & 1) * 8192;

#pragma unroll
        for (int mt = 0; mt < 2; ++mt) {
            floatx16 sc;
            __builtin_amdgcn_s_setprio(1);
            sc = MFA(LD_AK(B, mt, 0), qf[0], z);
            sc = MFA(LD_AK(B, mt, 1), qf[1], sc);
            sc = MFA(LD_AK(B, mt, 2), qf[2], sc);
            sc = MFA(LD_AK(B, mt, 3), qf[3], sc);
            __builtin_amdgcn_s_setprio(0);
            // exp2 (log2e folded into Q), packed pairwise sum (2 accumulators)
            floatx2 ps2[8];
#pragma unroll
            for (int i = 0; i < 8; ++i) {
                ps2[i][0] = fexp2(sc[2 * i]);
                ps2[i][1] = fexp2(sc[2 * i + 1]);
            }
#pragma unroll
            for (int i = 0; i < 8; i += 2) { rsA += ps2[i]; rsB += ps2[i + 1]; }
            unsigned pk[8];
#pragma unroll
            for (int i = 0; i < 8; ++i) {
                union { __hip_bfloat162 h; unsigned u; } cv;
                cv.h = __float22bfloat162_rn(make_float2(ps2[i][0], ps2[i][1]));
                pk[i] = cv.u;
            }
            // half-lane swaps: [pk0..pk3] = B-frag kv 0..15, [pk4..pk7] = kv 16..31
            lane32swap(pk[0], pk[2]);
            lane32swap(pk[1], pk[3]);
            lane32swap(pk[4], pk[6]);
            lane32swap(pk[5], pk[7]);
            __builtin_amdgcn_s_setprio(1);
#pragma unroll
            for (int ksl = 0; ksl < 2; ++ksl) {
                union { unsigned i[4]; shortx8 s8; } fr;
                fr.i[0] = pk[4 * ksl];     fr.i[1] = pk[4 * ksl + 1];
                fr.i[2] = pk[4 * ksl + 2]; fr.i[3] = pk[4 * ksl + 3];
#pragma unroll
                for (int mtd = 0; mtd < 2; ++mtd)
                    o[mtd] = MFA(LD_AV(B, mtd, mt, ksl), fr.s8, o[mtd]);
            }
            __builtin_amdgcn_s_setprio(0);
        }
    }
#undef STAGE
#undef LD_AK
#undef LD_AV
#undef MFA

    float rsum = rsA[0] + rsA[1] + rsB[0] + rsB[1];
    float tot = rsum + __shfl_xor(rsum, 32);
    float inv = 1.f / tot;

    __syncthreads();
    short* O_lds = Ls;   // 128 rows x 72 shorts = 18 KB, fits in 32 KB
#pragma unroll
    for (int mtd = 0; mtd < 2; ++mtd)
#pragma unroll
        for (int g = 0; g < 4; ++g) {
            shortx4 p4;
#pragma unroll
            for (int r = 0; r < 4; ++r) p4[r] = f2bs(o[mtd][4 * g + r] * inv);
            *(shortx4*)(O_lds + (w * 32 + l31) * 72 + mtd * 32 + g * 8 + hl * 4) = p4;
        }
    __syncthreads();
    const int b = bh >> 4, head = bh & 15;
#pragma unroll
    for (int it = 0; it < 4; ++it) {
        int idx = it * 256 + tid;
        int q = idx >> 3, ch = idx & 7;
        shortx8 v = *(const shortx8*)(O_lds + q * 72 + ch * 8);
        *(shortx8*)(ctx + ((size_t)(b * 2048 + q0 + q)) * 1024 + head * 64 + ch * 8) = v;
    }
}

// ---------------- launch ----------------
extern "C" void kernel_launch(void* const* d_in, const int* in_sizes, int n_in,
                              void* d_out, int out_size, void* d_ws, size_t ws_size,
                              hipStream_t stream) {
    const float* x   = (const float*)d_in[0];
    const float* wq  = (const float*)d_in[1];
    const float* wk  = (const float*)d_in[2];
    const float* wv  = (const float*)d_in[3];
    const float* wo  = (const float*)d_in[4];
    const float* w1  = (const float*)d_in[5];
    const float* b1  = (const float*)d_in[6];
    const float* w2  = (const float*)d_in[7];
    const float* b2  = (const float*)d_in[8];
    const float* g1p = (const float*)d_in[9];
    const float* be1 = (const float*)d_in[10];
    const float* g2p = (const float*)d_in[11];
    const float* be2 = (const float*)d_in[12];
    float* out = (float*)d_out;

    char* ws = (char*)d_ws;
    const size_t MB = 1ull << 20;
    short* wqt  = (short*)(ws + 0 * MB);
    short* wkt  = (short*)(ws + 2 * MB);
    short* wvt  = (short*)(ws + 4 * MB);
    short* wot  = (short*)(ws + 6 * MB);
    short* w1t  = (short*)(ws + 8 * MB);
    short* w2t  = (short*)(ws + 16 * MB);
    short* xb   = (short*)(ws + 24 * MB);
    short* Qb   = (short*)(ws + 40 * MB);   // K at +16MB, Vt at +32MB (EPI5 offsets)
    short* Kb   = (short*)(ws + 56 * MB);
    short* Vtg  = (short*)(ws + 72 * MB);
    short* ctxb = (short*)(ws + 88 * MB);
    float* tf   = (float*)(ws + 104 * MB);
    short* hb   = (short*)(ws + 136 * MB);
    short* f1b  = (short*)(ws + 40 * MB);   // reuses Qb..ctxb (dead by then)

    prep_kernel<<<5120, 256, 0, stream>>>(wq, wk, wv, wo, w1, w2, x,
                                          wqt, wkt, wvt, wot, w1t, w2t, xb);

    gemm256<5, 128><<<dim3(24, 32), 512, 0, stream>>>(xb, wqt, 1024, 3072, Qb, nullptr, nullptr, nullptr);
    attn_kernel<<<dim3(64, 16), 256, 0, stream>>>(Qb, Kb, Vtg, ctxb);
    gemm256<2, 128><<<dim3(8, 32), 512, 0, stream>>>(ctxb, wot, 1024, 1024, nullptr, tf, nullptr, x);
    ln_kernel<<<8192, 256, 0, stream>>>(tf, tf, hb, g1p, be1, 1);
    gemm256<1, 256><<<dim3(16, 32), 512, 0, stream>>>(hb, w1t, 1024, 4096, f1b, nullptr, b1, nullptr);
    gemm256<3, 128><<<dim3(8, 32), 512, 0, stream>>>(f1b, w2t, 4096, 1024, nullptr, out, b2, tf);
    ln_kernel<<<8192, 256, 0, stream>>>(out, out, nullptr, g2p, be2, 0);
}